// Round 4
// baseline (1115.257 us; speedup 1.0000x reference)
//
#include <hip/hip_runtime.h>

// SegDecoder: 3-layer cross-attention decoder on MI355X (gfx950).
// B=16, Nq=64, Nk=4096, C=512, H=8, hd=64, FF=2048, L=3.
// R4: double-buffered LDS + cross-tile global_load_lds prefetch (2-phase),
// bijective XCD-chunk block swizzle on all GEMMs.

typedef unsigned short u16;
typedef __attribute__((ext_vector_type(8))) short short8;
typedef __attribute__((ext_vector_type(4))) short short4v;
typedef __attribute__((ext_vector_type(4))) float f32x4;

__device__ __forceinline__ float b2f(u16 u) {
    union { unsigned int i; float f; } v; v.i = ((unsigned int)u) << 16; return v.f;
}
__device__ __forceinline__ u16 f2b(float f) {  // round-to-nearest-even
    unsigned int x = __float_as_uint(f);
    x += 0x7fffu + ((x >> 16) & 1u);
    return (u16)(x >> 16);
}

__device__ __forceinline__ float waveSum(float v) {
#pragma unroll
    for (int o = 32; o > 0; o >>= 1) v += __shfl_xor(v, o);
    return v;
}
__device__ __forceinline__ float waveMax(float v) {
#pragma unroll
    for (int o = 32; o > 0; o >>= 1) v = fmaxf(v, __shfl_xor(v, o));
    return v;
}

// async global->LDS, 16B per lane. LDS dest is wave-uniform base + lane*16.
__device__ __forceinline__ void gl_lds16(const void* g, void* l) {
    __builtin_amdgcn_global_load_lds(
        (__attribute__((address_space(1))) void*)g,
        (__attribute__((address_space(3))) void*)l, 16, 0, 0);
}

// ---------------------------------------------------------------------------
// Generic batched GEMM:  C = alpha * A(M,K) @ Bt(N,K)^T [+ bias][*affc][relu]
// BK=64 rows of 128B (8 x 16B units), unit swizzle u^(row&7), double-buffered
// LDS with cross-tile prefetch: stage(next) -> compute(cur) -> one barrier.
// Block ids remapped so each XCD gets a contiguous chunk of tiles (L2 reuse).
// SMAX: A holds bf16 scores s; fragment transform p=exp(s-m)*inv from stats.
// AFFC: epilogue *= affc[zq*4096 + col].
// ---------------------------------------------------------------------------
template<int TM, int TN, bool OUT_BF16, bool RELU, bool BIAS_ROW, bool HAS_BIAS,
         bool AFFC, bool SMAX>
__global__ __launch_bounds__(256) void gemm_bt_k(
    const u16* __restrict__ A, const u16* __restrict__ Bt,
    const float* __restrict__ bias, void* __restrict__ Cout,
    int K, int lda, int ldb, int ldc,
    int bdiv, long sA1, long sA2, long sB1, long sB2, long sC1, long sC2,
    float alpha, const float* __restrict__ affc, const float2* __restrict__ stats)
{
    __shared__ u16 As[2][TM][64];
    __shared__ u16 Bs[2][TN][64];
    const int t = threadIdx.x;
    const int lane = t & 63;
    const int wave = t >> 6;

    // bijective XCD-chunk swizzle (m204): XCD x gets a contiguous tile chunk
    const int gx = gridDim.x, gy = gridDim.y;
    const int nwg = gx * gy * gridDim.z;
    int id;
    {
        const int orig = blockIdx.x + blockIdx.y * gx + blockIdx.z * gx * gy;
        const int qq = nwg >> 3, rr = nwg & 7;
        const int xcd = orig & 7, sub = orig >> 3;
        id = (xcd < rr ? xcd * (qq + 1) : rr * (qq + 1) + (xcd - rr) * qq) + sub;
    }
    const int bx = id % gx;
    const int by = (id / gx) % gy;
    const int z  = id / (gx * gy);

    const int zq = z / bdiv, zr = z % bdiv;
    A  += (long)zq * sA1 + (long)zr * sA2;
    Bt += (long)zq * sB1 + (long)zr * sB2;
    const long cbase = (long)zq * sC1 + (long)zr * sC2;
    const int n0 = bx * TN;
    const int m0 = by * TM;
    constexpr int FM = TM / 32, FN = TN / 32;
    const int wr = wave >> 1, wc = wave & 1;
    const int rl = lane & 15, uq = lane >> 4;

    float2 st[FM];
    if constexpr (SMAX) {
#pragma unroll
        for (int i = 0; i < FM; ++i)
            st[i] = stats[zr * 64 + m0 + wr * (TM / 2) + i * 16 + rl];
    }

    f32x4 acc[FM][FN];
#pragma unroll
    for (int i = 0; i < FM; ++i)
#pragma unroll
        for (int j = 0; j < FN; ++j) acc[i][j] = (f32x4){0.f, 0.f, 0.f, 0.f};

    // staging: one issue = 8 rows x 128B = 1KB; srow in [0,8), up = 16B unit
    const int srow = lane >> 3;
    const int up   = lane & 7;

    auto stage = [&](int buf, int k0) {
#pragma unroll
        for (int r = 0; r < TM / 32; ++r) {
            const int br = (wave * (TM / 32) + r) * 8;
            const int row = br + srow;
            const int ul = up ^ (row & 7);
            gl_lds16(A + (long)(m0 + row) * lda + k0 + ul * 8, &As[buf][br][0]);
        }
#pragma unroll
        for (int r = 0; r < TN / 32; ++r) {
            const int br = (wave * (TN / 32) + r) * 8;
            const int row = br + srow;
            const int ul = up ^ (row & 7);
            gl_lds16(Bt + (long)(n0 + row) * ldb + k0 + ul * 8, &Bs[buf][br][0]);
        }
    };

    auto compute = [&](int buf) {
#pragma unroll
        for (int kc = 0; kc < 2; ++kc) {
            short8 af[FM], bf[FN];
#pragma unroll
            for (int i = 0; i < FM; ++i) {
                const int R = wr * (TM / 2) + i * 16 + rl;
                af[i] = *(const short8*)(&As[buf][R][((kc * 4 + uq) ^ (R & 7)) * 8]);
                if constexpr (SMAX) {
#pragma unroll
                    for (int e = 0; e < 8; ++e)
                        af[i][e] = (short)f2b(
                            __expf(b2f((u16)af[i][e]) - st[i].x) * st[i].y);
                }
            }
#pragma unroll
            for (int j = 0; j < FN; ++j) {
                const int R = wc * (TN / 2) + j * 16 + rl;
                bf[j] = *(const short8*)(&Bs[buf][R][((kc * 4 + uq) ^ (R & 7)) * 8]);
            }
#pragma unroll
            for (int i = 0; i < FM; ++i)
#pragma unroll
                for (int j = 0; j < FN; ++j)
                    acc[i][j] = __builtin_amdgcn_mfma_f32_16x16x32_bf16(
                        af[i], bf[j], acc[i][j], 0, 0, 0);
        }
    };

    // 2-phase pipeline: stage(next) issued before compute(cur); single
    // __syncthreads per K-tile (drains vmcnt+lgkmcnt, then barrier).
    stage(0, 0);
    __syncthreads();
    for (int k0 = 0; k0 < K; k0 += 128) {
        if (k0 + 64 < K) stage(1, k0 + 64);
        compute(0);
        __syncthreads();
        if (k0 + 64 >= K) break;
        if (k0 + 128 < K) stage(0, k0 + 128);
        compute(1);
        __syncthreads();
    }

    const int r0 = (lane >> 4) * 4;
    const int c0 = lane & 15;
#pragma unroll
    for (int i = 0; i < FM; ++i) {
#pragma unroll
        for (int j = 0; j < FN; ++j) {
#pragma unroll
            for (int r = 0; r < 4; ++r) {
                const int row = m0 + wr * (TM / 2) + i * 16 + r0 + r;
                const int col = n0 + wc * (TN / 2) + j * 16 + c0;
                float v = acc[i][j][r] * alpha;
                if constexpr (HAS_BIAS) {
                    if constexpr (BIAS_ROW) v += bias[row]; else v += bias[col];
                }
                if constexpr (AFFC) v *= affc[(long)zq * 4096 + col];
                if constexpr (RELU) v = fmaxf(v, 0.f);
                const long idx = cbase + (long)row * ldc + col;
                if constexpr (OUT_BF16) ((u16*)Cout)[idx] = f2b(v);
                else                    ((float*)Cout)[idx] = v;
            }
        }
    }
}

// ---------------------------------------------------------------------------
// softmax stats (m, 1/sum) per (b,h,q) + head-averaged score output.
// block = (b,q); S layout (B,H,64,4096) bf16; attns (B,64,4096) fp32.
// ---------------------------------------------------------------------------
__global__ __launch_bounds__(256) void smstats_k(
    const u16* __restrict__ S, float2* __restrict__ stats,
    float* __restrict__ attns)
{
    const int bq = blockIdx.x;
    const int b = bq >> 6, q = bq & 63;
    const int t = threadIdx.x;
    const int w = t >> 6, lane = t & 63;
    __shared__ float red[4];
    const int kb = t * 16;

    float attnacc[16];
#pragma unroll
    for (int j = 0; j < 16; ++j) attnacc[j] = 0.f;

    for (int h = 0; h < 8; ++h) {
        const long roff = (((long)(b * 8 + h)) * 64 + q) * 4096;
        const u16* Srow = S + roff;
        float v[16];
        short8 s0 = *(const short8*)(Srow + kb);
        short8 s1 = *(const short8*)(Srow + kb + 8);
#pragma unroll
        for (int j = 0; j < 8; ++j) { v[j] = b2f((u16)s0[j]); v[8 + j] = b2f((u16)s1[j]); }

        float m = -3.0e38f;
#pragma unroll
        for (int j = 0; j < 16; ++j) m = fmaxf(m, v[j]);
        m = waveMax(m);
        __syncthreads();
        if (lane == 0) red[w] = m;
        __syncthreads();
        m = fmaxf(fmaxf(red[0], red[1]), fmaxf(red[2], red[3]));

        float s = 0.f;
#pragma unroll
        for (int j = 0; j < 16; ++j) s += __expf(v[j] - m);
        s = waveSum(s);
        __syncthreads();
        if (lane == 0) red[w] = s;
        __syncthreads();
        s = red[0] + red[1] + red[2] + red[3];

        if (t == 0) stats[(b * 8 + h) * 64 + q] = make_float2(m, 1.f / s);
#pragma unroll
        for (int j = 0; j < 16; ++j) attnacc[j] += v[j];
    }
    float* arow = attns + (long)bq * 4096;
#pragma unroll
    for (int j = 0; j < 16; ++j) arow[kb + j] = attnacc[j] * 0.125f;  // /H
}

// ---------------------------------------------------------------------------
// split-K PV reduce: part (8,128,64,64) fp32 -> o16 (16,64,512) bf16
// ---------------------------------------------------------------------------
__global__ __launch_bounds__(256) void pv_reduce_k(
    const float* __restrict__ part, u16* __restrict__ o16)
{
    const int i = blockIdx.x * 256 + threadIdx.x;   // 131072 threads x 4 elems
    const int d4 = i & 15;
    const int q  = (i >> 4) & 63;
    const int bh = i >> 10;                          // 0..127
    const float* p = part + (long)bh * 4096 + q * 64 + d4 * 4;
    float4 s = {0.f, 0.f, 0.f, 0.f};
#pragma unroll
    for (int sp = 0; sp < 8; ++sp) {
        const float4 v = *(const float4*)(p + (long)sp * 524288);
        s.x += v.x; s.y += v.y; s.z += v.z; s.w += v.w;
    }
    const int b = bh >> 3, h = bh & 7;
    u16* o = o16 + (long)b * 32768 + q * 512 + h * 64 + d4 * 4;
    short4v r;
    r[0] = (short)f2b(s.x); r[1] = (short)f2b(s.y);
    r[2] = (short)f2b(s.z); r[3] = (short)f2b(s.w);
    *(short4v*)o = r;
}

// split-K FF2 reduce + bias: part (4,1024,512) fp32 -> out (1024,512) fp32
__global__ __launch_bounds__(256) void ffred_k(
    const float* __restrict__ part, const float* __restrict__ bias,
    float* __restrict__ out)
{
    const int i = (blockIdx.x * 256 + threadIdx.x) * 4;  // grid 512
    const int c = i & 511;
    float4 s = *(const float4*)(part + i);
#pragma unroll
    for (int sp = 1; sp < 4; ++sp) {
        const float4 v = *(const float4*)(part + (long)sp * 524288 + i);
        s.x += v.x; s.y += v.y; s.z += v.z; s.w += v.w;
    }
    s.x += bias[c]; s.y += bias[c + 1]; s.z += bias[c + 2]; s.w += bias[c + 3];
    *(float4*)(out + i) = s;
}

// ---------------------------------------------------------------------------
// u[l][b][c'] = sum_c Wk[l][c'][c] * extra[b][c]   (for the aff gate)
// ---------------------------------------------------------------------------
__global__ __launch_bounds__(256) void umat_k(
    const float* __restrict__ Wk, const float* __restrict__ extra,
    float* __restrict__ u)
{
    __shared__ float ex[16][512];
    const int l = blockIdx.x;
    const int t = threadIdx.x;
    for (int i = t; i < 16 * 512 / 4; i += 256)
        ((float4*)&ex[0][0])[i] = ((const float4*)extra)[i];
    __syncthreads();
    const int lane = t & 63, wave = t >> 6;
    const int row = blockIdx.y * 4 + wave;          // c' in [0,512)
    const float* wrow = Wk + ((size_t)l * 512 + row) * 512 + lane * 8;
    float w[8];
#pragma unroll
    for (int j = 0; j < 8; ++j) w[j] = wrow[j];
    float s[16];
#pragma unroll
    for (int b = 0; b < 16; ++b) {
        float x = 0.f;
#pragma unroll
        for (int j = 0; j < 8; ++j) x += w[j] * ex[b][lane * 8 + j];
        s[b] = waveSum(x);
    }
    if (lane < 16) u[((size_t)l * 16 + lane) * 512 + row] = s[lane];
}

// cb[l*16+b] = dot(extra[b], bk[l])
__global__ __launch_bounds__(256) void cbk_k(
    const float* __restrict__ bk, const float* __restrict__ extra,
    float* __restrict__ cb)
{
    const int gw = blockIdx.x * 4 + (threadIdx.x >> 6);  // 48 waves
    const int lane = threadIdx.x & 63;
    const int l = gw >> 4, b = gw & 15;
    float s = 0.f;
#pragma unroll
    for (int j = 0; j < 8; ++j)
        s += extra[b * 512 + lane * 8 + j] * bk[l * 512 + lane * 8 + j];
    s = waveSum(s);
    if (lane == 0) cb[gw] = s;
}

// ---------------------------------------------------------------------------
// feat fp32 -> bf16, fused with aff for all 3 layers:
// aff[l][b][k] = sigmoid(SCALE/H * (feat[b,k,:]·u[l][b] + cb[l][b]))
// ---------------------------------------------------------------------------
__global__ __launch_bounds__(256) void cvt16_aff_k(
    const float* __restrict__ feat, u16* __restrict__ dst,
    const float* __restrict__ u, const float* __restrict__ cb,
    float* __restrict__ affb, float* __restrict__ affs_out)
{
    const int t = blockIdx.x * 256 + threadIdx.x;
    const long i = (long)t * 8;
    const int lane = threadIdx.x & 63;
    const int r = t >> 6;           // row (b*4096 + k)
    const int b = r >> 12;
    const float4 a0 = *(const float4*)(feat + i);
    const float4 a1 = *(const float4*)(feat + i + 4);
    short8 o;
    o[0] = (short)f2b(a0.x); o[1] = (short)f2b(a0.y);
    o[2] = (short)f2b(a0.z); o[3] = (short)f2b(a0.w);
    o[4] = (short)f2b(a1.x); o[5] = (short)f2b(a1.y);
    o[6] = (short)f2b(a1.z); o[7] = (short)f2b(a1.w);
    *(short8*)(dst + i) = o;
    const float f[8] = {a0.x, a0.y, a0.z, a0.w, a1.x, a1.y, a1.z, a1.w};
#pragma unroll
    for (int l = 0; l < 3; ++l) {
        const float* ur = u + ((size_t)l * 16 + b) * 512 + lane * 8;
        float s = 0.f;
#pragma unroll
        for (int j = 0; j < 8; ++j) s += f[j] * ur[j];
        s = waveSum(s);
        if (lane == 0) {
            const float av = 1.f / (1.f + __expf(-0.015625f * (s + cb[l * 16 + b])));
            affb[l * 65536 + r] = av;
            affs_out[l * 65536 + r] = av;
        }
    }
}

// ---------------------------------------------------------------------------
// x = LN(x + add; g, beta); updates x (fp32) and x16 (bf16); optional out copy.
// ---------------------------------------------------------------------------
template<bool WRITE_OUT>
__global__ __launch_bounds__(256) void ln_k(
    float* __restrict__ x, const float* __restrict__ add,
    const float* __restrict__ g, const float* __restrict__ be,
    u16* __restrict__ x16, float* __restrict__ outp)
{
    const int r = blockIdx.x, t = threadIdx.x;
    const int w = t >> 6, lane = t & 63;
    __shared__ float red[4];
    float* xr = x + (long)r * 512;
    const float* ar = add + (long)r * 512;
    const float v0 = xr[2 * t]     + ar[2 * t];
    const float v1 = xr[2 * t + 1] + ar[2 * t + 1];
    float s = waveSum(v0 + v1);
    if (lane == 0) red[w] = s;
    __syncthreads();
    s = red[0] + red[1] + red[2] + red[3];
    const float mu = s * (1.f / 512.f);
    const float d0 = v0 - mu, d1 = v1 - mu;
    __syncthreads();
    float vs = waveSum(d0 * d0 + d1 * d1);
    if (lane == 0) red[w] = vs;
    __syncthreads();
    vs = red[0] + red[1] + red[2] + red[3];
    const float rs = rsqrtf(vs * (1.f / 512.f) + 1e-5f);
    const float o0 = g[2 * t]     * d0 * rs + be[2 * t];
    const float o1 = g[2 * t + 1] * d1 * rs + be[2 * t + 1];
    xr[2 * t] = o0; xr[2 * t + 1] = o1;
    x16[(long)r * 512 + 2 * t]     = f2b(o0);
    x16[(long)r * 512 + 2 * t + 1] = f2b(o1);
    if constexpr (WRITE_OUT) {
        outp[(long)r * 512 + 2 * t]     = o0;
        outp[(long)r * 512 + 2 * t + 1] = o1;
    }
}

// x = copy(queries) fp32 + bf16
__global__ __launch_bounds__(256) void initx_k(
    const float* __restrict__ src, float* __restrict__ x, u16* __restrict__ x16)
{
    const long i = ((long)blockIdx.x * 256 + threadIdx.x) * 8;
    const float4 a = *(const float4*)(src + i);
    const float4 b = *(const float4*)(src + i + 4);
    *(float4*)(x + i) = a;
    *(float4*)(x + i + 4) = b;
    short8 r;
    r[0] = (short)f2b(a.x); r[1] = (short)f2b(a.y); r[2] = (short)f2b(a.z); r[3] = (short)f2b(a.w);
    r[4] = (short)f2b(b.x); r[5] = (short)f2b(b.y); r[6] = (short)f2b(b.z); r[7] = (short)f2b(b.w);
    *(short8*)(x16 + i) = r;
}

// W (K,N) fp32 -> WT (N,K) bf16, batched over blockIdx.z
__global__ __launch_bounds__(256) void transpose_w_k(
    const float* __restrict__ W, u16* __restrict__ WT, int K, int N)
{
    __shared__ float tile[32][33];
    const int z = blockIdx.z;
    W  += (size_t)z * K * N;
    WT += (size_t)z * K * N;
    const int n0 = blockIdx.x * 32, k0 = blockIdx.y * 32;
    const int tx = threadIdx.x & 31, ty = threadIdx.x >> 5;
#pragma unroll
    for (int j = 0; j < 32; j += 8)
        tile[ty + j][tx] = W[(size_t)(k0 + ty + j) * N + n0 + tx];
    __syncthreads();
#pragma unroll
    for (int j = 0; j < 32; j += 8)
        WT[(size_t)(n0 + ty + j) * K + k0 + tx] = f2b(tile[tx][ty + j]);
}

// ---------------------------------------------------------------------------
extern "C" void kernel_launch(void* const* d_in, const int* in_sizes, int n_in,
                              void* d_out, int out_size, void* d_ws, size_t ws_size,
                              hipStream_t stream)
{
    (void)in_sizes; (void)n_in; (void)out_size; (void)ws_size;
    const float* queries = (const float*)d_in[0];
    const float* feat    = (const float*)d_in[1];
    const float* extra   = (const float*)d_in[2];
    const float* Wq = (const float*)d_in[3];  const float* bq = (const float*)d_in[4];
    const float* Wk = (const float*)d_in[5];  const float* bk = (const float*)d_in[6];
    const float* Wv = (const float*)d_in[7];  const float* bv = (const float*)d_in[8];
    const float* Wo = (const float*)d_in[9];  const float* bo = (const float*)d_in[10];
    const float* W1 = (const float*)d_in[11]; const float* b1 = (const float*)d_in[12];
    const float* W2 = (const float*)d_in[13]; const float* b2 = (const float*)d_in[14];
    const float* g2 = (const float*)d_in[15]; const float* be2 = (const float*)d_in[16];
    const float* g3 = (const float*)d_in[17]; const float* be3 = (const float*)d_in[18];

    char* wsb = (char*)d_ws;
    size_t off = 0;
    auto alloc = [&](size_t bytes) -> char* {
        char* p = wsb + off; off += (bytes + 255) & ~(size_t)255; return p;
    };
    u16*  feat16 = (u16*)alloc(33554432ull * 2);   // (B*Nk, C) bf16
    u16*  WqT = (u16*)alloc(786432ull * 2);        // (L,512,512) transposed
    u16*  WkT = (u16*)alloc(786432ull * 2);
    u16*  WvT = (u16*)alloc(786432ull * 2);
    u16*  WoT = (u16*)alloc(786432ull * 2);
    u16*  W1T = (u16*)alloc(3145728ull * 2);       // (L,2048,512)
    u16*  W2T = (u16*)alloc(3145728ull * 2);       // (L,512,2048)
    u16*  K16 = (u16*)alloc(33554432ull * 2);      // (B,Nk,C); later PV partials
    u16*  VT16 = (u16*)alloc(33554432ull * 2);     // (B,C,Nk) aff-gated; later FF2 partials
    u16*  q16 = (u16*)alloc(524288ull * 2);        // (B*Nq, C)
    u16*  S16 = (u16*)alloc(33554432ull * 2);      // (B,H,64,4096) scores*SCALE
    float* affb  = (float*)alloc(196608ull * 4);   // (L,B,Nk)
    u16*  o16 = (u16*)alloc(524288ull * 2);        // attention out (B,Nq,C)
    float* oproj = (float*)alloc(524288ull * 4);
    float* xb    = (float*)alloc(524288ull * 4);
    u16*  x16 = (u16*)alloc(524288ull * 2);
    u16*  h116 = (u16*)alloc(2097152ull * 2);      // (B*Nq, 2048)
    float* ffb   = (float*)alloc(524288ull * 4);
    float* uvec  = (float*)alloc(24576ull * 4);    // (L,16,512)
    float* cb    = (float*)alloc(48ull * 4);
    float2* stats = (float2*)alloc(8192ull * 8);   // (B*H*64) {m, 1/sum}
    float* partPV = (float*)K16;                   // alias: K dead after S-GEMM
    float* part2  = (float*)VT16;                  // alias: VT dead after PV

    float* out_f = (float*)d_out;
    float* outs_base  = out_f;                     // (3,16,64,512)
    float* attns_base = out_f + 1572864;           // (3,16,64,4096)
    float* affs_base  = out_f + 14155776;          // (3,16,1,1,4096)

    // prep (layer-independent)
    umat_k<<<dim3(3, 128), 256, 0, stream>>>(Wk, extra, uvec);
    cbk_k<<<12, 256, 0, stream>>>(bk, extra, cb);
    cvt16_aff_k<<<16384, 256, 0, stream>>>(feat, feat16, uvec, cb, affb, affs_base);
    initx_k<<<256, 256, 0, stream>>>(queries, xb, x16);
    transpose_w_k<<<dim3(16, 16, 3), 256, 0, stream>>>(Wq, WqT, 512, 512);
    transpose_w_k<<<dim3(16, 16, 3), 256, 0, stream>>>(Wk, WkT, 512, 512);
    transpose_w_k<<<dim3(16, 16, 3), 256, 0, stream>>>(Wv, WvT, 512, 512);
    transpose_w_k<<<dim3(16, 16, 3), 256, 0, stream>>>(Wo, WoT, 512, 512);
    transpose_w_k<<<dim3(64, 16, 3), 256, 0, stream>>>(W1, W1T, 512, 2048);
    transpose_w_k<<<dim3(16, 64, 3), 256, 0, stream>>>(W2, W2T, 2048, 512);

    for (int i = 0; i < 3; ++i) {
        // K = feat @ Wk + bk   (M=65536, N=512, K=512) -> bf16 (B,Nk,C)
        gemm_bt_k<128, 128, true, false, false, true, false, false>
            <<<dim3(4, 512, 1), 256, 0, stream>>>(
            feat16, WkT + i * 262144, bk + i * 512, K16,
            512, 512, 512, 512, 1, 0, 0, 0, 0, 0, 0, 1.f, nullptr, nullptr);
        // VT'[b] = aff ⊙ ((feat[b] @ Wv)^T + bv)  -> (B,C,Nk)
        gemm_bt_k<128, 128, true, false, true, true, true, false>
            <<<dim3(32, 4, 16), 256, 0, stream>>>(
            WvT + i * 262144, feat16, bv + i * 512, VT16,
            512, 512, 512, 4096, 1, 0, 0, 2097152, 0, 2097152, 0, 1.f,
            affb + i * 65536, nullptr);
        // q = x @ Wq + bq  (1024 x 512)
        gemm_bt_k<64, 64, true, false, false, true, false, false>
            <<<dim3(8, 16, 1), 256, 0, stream>>>(
            x16, WqT + i * 262144, bq + i * 512, q16,
            512, 512, 512, 512, 1, 0, 0, 0, 0, 0, 0, 1.f, nullptr, nullptr);
        // S[b,h] = SCALE * q_h @ K_h^T   (batch 128: M=64,N=4096,K=64)
        gemm_bt_k<64, 128, true, false, false, false, false, false>
            <<<dim3(32, 1, 128), 256, 0, stream>>>(
            q16, K16, nullptr, S16,
            64, 512, 512, 4096, 8, 32768, 64, 2097152, 64, 2097152, 262144,
            0.125f, nullptr, nullptr);
        // softmax stats + attns
        smstats_k<<<1024, 256, 0, stream>>>(
            S16, stats, attns_base + (size_t)i * 4194304);
        // o[b,h] = softmax(S) @ V', split-K 8, softmax fused at fragment load
        gemm_bt_k<64, 64, false, false, false, false, false, true>
            <<<dim3(1, 1, 1024), 256, 0, stream>>>(
            S16, VT16, nullptr, partPV,
            512, 4096, 4096, 64, 128, 512, 262144, 512, 262144, 524288, 4096,
            1.f, nullptr, stats);
        pv_reduce_k<<<512, 256, 0, stream>>>(partPV, o16);
        // o @ Wo + bo -> fp32
        gemm_bt_k<64, 64, false, false, false, true, false, false>
            <<<dim3(8, 16, 1), 256, 0, stream>>>(
            o16, WoT + i * 262144, bo + i * 512, oproj,
            512, 512, 512, 512, 1, 0, 0, 0, 0, 0, 0, 1.f, nullptr, nullptr);
        // x = LN(x + oproj; g2, beta2)
        ln_k<false><<<1024, 256, 0, stream>>>(xb, oproj, g2 + i * 512, be2 + i * 512, x16, nullptr);
        // h1 = relu(x @ W1 + b1) -> bf16 (1024 x 2048)
        gemm_bt_k<64, 128, true, true, false, true, false, false>
            <<<dim3(16, 16, 1), 256, 0, stream>>>(
            x16, W1T + (size_t)i * 1048576, b1 + i * 2048, h116,
            512, 512, 512, 2048, 1, 0, 0, 0, 0, 0, 0, 1.f, nullptr, nullptr);
        // ff partials = h1 @ W2 (split-K 4) -> fp32 (4,1024,512)
        gemm_bt_k<64, 64, false, false, false, false, false, false>
            <<<dim3(8, 16, 4), 256, 0, stream>>>(
            h116, W2T + (size_t)i * 1048576, nullptr, part2,
            512, 2048, 2048, 512, 1, 512, 0, 512, 0, 524288, 0,
            1.f, nullptr, nullptr);
        ffred_k<<<512, 256, 0, stream>>>(part2, b2 + i * 512, ffb);
        // x = LN(x + ff; g3, beta3), write outs[i]
        ln_k<true><<<1024, 256, 0, stream>>>(xb, ffb, g3 + i * 512, be3 + i * 512, x16,
                                             outs_base + (size_t)i * 524288);
    }
}

// Round 5
// 848.435 us; speedup vs baseline: 1.3145x; 1.3145x over previous
//
#include <hip/hip_runtime.h>

// SegDecoder: 3-layer cross-attention decoder on MI355X (gfx950).
// B=16, Nq=64, Nk=4096, C=512, H=8, hd=64, FF=2048, L=3.
// R5: R3's single-buffered BK=64 GEMM (32KB LDS, proven 19.9% occ) +
// bijective XCD-chunk swizzle (proven FETCH 133->35MB in R4).
// R4's 64KB double-buffer REVERTED (occupancy regression, m132 mode).

typedef unsigned short u16;
typedef __attribute__((ext_vector_type(8))) short short8;
typedef __attribute__((ext_vector_type(4))) short short4v;
typedef __attribute__((ext_vector_type(4))) float f32x4;

__device__ __forceinline__ float b2f(u16 u) {
    union { unsigned int i; float f; } v; v.i = ((unsigned int)u) << 16; return v.f;
}
__device__ __forceinline__ u16 f2b(float f) {  // round-to-nearest-even
    unsigned int x = __float_as_uint(f);
    x += 0x7fffu + ((x >> 16) & 1u);
    return (u16)(x >> 16);
}

__device__ __forceinline__ float waveSum(float v) {
#pragma unroll
    for (int o = 32; o > 0; o >>= 1) v += __shfl_xor(v, o);
    return v;
}
__device__ __forceinline__ float waveMax(float v) {
#pragma unroll
    for (int o = 32; o > 0; o >>= 1) v = fmaxf(v, __shfl_xor(v, o));
    return v;
}

// async global->LDS, 16B per lane. LDS dest is wave-uniform base + lane*16.
__device__ __forceinline__ void gl_lds16(const void* g, void* l) {
    __builtin_amdgcn_global_load_lds(
        (__attribute__((address_space(1))) void*)g,
        (__attribute__((address_space(3))) void*)l, 16, 0, 0);
}

// ---------------------------------------------------------------------------
// Generic batched GEMM:  C = alpha * A(M,K) @ Bt(N,K)^T [+ bias][*affc][relu]
// BK=64: LDS rows of 64 bf16 (128B = 8 x 16B units), unit swizzle u^(row&7).
// Single-buffered (32KB LDS -> ~5 blocks/CU ceiling). Block ids remapped so
// each XCD gets a contiguous chunk of tiles (L2 reuse, bijective m204 form).
// SMAX: A holds bf16 scores s; fragment transform p=exp(s-m)*inv from stats.
// AFFC: epilogue *= affc[zq*4096 + col].
// ---------------------------------------------------------------------------
template<int TM, int TN, bool OUT_BF16, bool RELU, bool BIAS_ROW, bool HAS_BIAS,
         bool AFFC, bool SMAX>
__global__ __launch_bounds__(256) void gemm_bt_k(
    const u16* __restrict__ A, const u16* __restrict__ Bt,
    const float* __restrict__ bias, void* __restrict__ Cout,
    int K, int lda, int ldb, int ldc,
    int bdiv, long sA1, long sA2, long sB1, long sB2, long sC1, long sC2,
    float alpha, const float* __restrict__ affc, const float2* __restrict__ stats)
{
    __shared__ u16 As[TM][64];
    __shared__ u16 Bs[TN][64];
    const int t = threadIdx.x;
    const int lane = t & 63;
    const int wave = t >> 6;

    // bijective XCD-chunk swizzle (m204): XCD x gets a contiguous tile chunk
    const int gx = gridDim.x, gy = gridDim.y;
    const int nwg = gx * gy * gridDim.z;
    int id;
    {
        const int orig = blockIdx.x + blockIdx.y * gx + blockIdx.z * gx * gy;
        const int qq = nwg >> 3, rr = nwg & 7;
        const int xcd = orig & 7, sub = orig >> 3;
        id = (xcd < rr ? xcd * (qq + 1) : rr * (qq + 1) + (xcd - rr) * qq) + sub;
    }
    const int bx = id % gx;
    const int by = (id / gx) % gy;
    const int z  = id / (gx * gy);

    const int zq = z / bdiv, zr = z % bdiv;
    A  += (long)zq * sA1 + (long)zr * sA2;
    Bt += (long)zq * sB1 + (long)zr * sB2;
    const long cbase = (long)zq * sC1 + (long)zr * sC2;
    const int n0 = bx * TN;
    const int m0 = by * TM;
    constexpr int FM = TM / 32, FN = TN / 32;
    const int wr = wave >> 1, wc = wave & 1;
    const int rl = lane & 15, uq = lane >> 4;

    float2 st[FM];
    if constexpr (SMAX) {
#pragma unroll
        for (int i = 0; i < FM; ++i)
            st[i] = stats[zr * 64 + m0 + wr * (TM / 2) + i * 16 + rl];
    }

    f32x4 acc[FM][FN];
#pragma unroll
    for (int i = 0; i < FM; ++i)
#pragma unroll
        for (int j = 0; j < FN; ++j) acc[i][j] = (f32x4){0.f, 0.f, 0.f, 0.f};

    // staging: one issue = 8 rows x 128B = 1KB; srow in [0,8), up = 16B unit
    const int srow = lane >> 3;
    const int up   = lane & 7;

    for (int k0 = 0; k0 < K; k0 += 64) {
        __syncthreads();
#pragma unroll
        for (int r = 0; r < TM / 32; ++r) {
            const int br = (wave * (TM / 32) + r) * 8;
            const int row = br + srow;
            const int ul = up ^ (row & 7);
            gl_lds16(A + (long)(m0 + row) * lda + k0 + ul * 8, &As[br][0]);
        }
#pragma unroll
        for (int r = 0; r < TN / 32; ++r) {
            const int br = (wave * (TN / 32) + r) * 8;
            const int row = br + srow;
            const int ul = up ^ (row & 7);
            gl_lds16(Bt + (long)(n0 + row) * ldb + k0 + ul * 8, &Bs[br][0]);
        }
        __syncthreads();   // drains vmcnt (global_load_lds)

#pragma unroll
        for (int kc = 0; kc < 2; ++kc) {
            short8 af[FM], bf[FN];
#pragma unroll
            for (int i = 0; i < FM; ++i) {
                const int R = wr * (TM / 2) + i * 16 + rl;
                af[i] = *(const short8*)(&As[R][((kc * 4 + uq) ^ (R & 7)) * 8]);
                if constexpr (SMAX) {
#pragma unroll
                    for (int e = 0; e < 8; ++e)
                        af[i][e] = (short)f2b(
                            __expf(b2f((u16)af[i][e]) - st[i].x) * st[i].y);
                }
            }
#pragma unroll
            for (int j = 0; j < FN; ++j) {
                const int R = wc * (TN / 2) + j * 16 + rl;
                bf[j] = *(const short8*)(&Bs[R][((kc * 4 + uq) ^ (R & 7)) * 8]);
            }
#pragma unroll
            for (int i = 0; i < FM; ++i)
#pragma unroll
                for (int j = 0; j < FN; ++j)
                    acc[i][j] = __builtin_amdgcn_mfma_f32_16x16x32_bf16(
                        af[i], bf[j], acc[i][j], 0, 0, 0);
        }
    }

    const int r0 = (lane >> 4) * 4;
    const int c0 = lane & 15;
#pragma unroll
    for (int i = 0; i < FM; ++i) {
#pragma unroll
        for (int j = 0; j < FN; ++j) {
#pragma unroll
            for (int r = 0; r < 4; ++r) {
                const int row = m0 + wr * (TM / 2) + i * 16 + r0 + r;
                const int col = n0 + wc * (TN / 2) + j * 16 + c0;
                float v = acc[i][j][r] * alpha;
                if constexpr (HAS_BIAS) {
                    if constexpr (BIAS_ROW) v += bias[row]; else v += bias[col];
                }
                if constexpr (AFFC) v *= affc[(long)zq * 4096 + col];
                if constexpr (RELU) v = fmaxf(v, 0.f);
                const long idx = cbase + (long)row * ldc + col;
                if constexpr (OUT_BF16) ((u16*)Cout)[idx] = f2b(v);
                else                    ((float*)Cout)[idx] = v;
            }
        }
    }
}

// ---------------------------------------------------------------------------
// softmax stats (m, 1/sum) per (b,h,q) + head-averaged score output.
// block = (b,q); S layout (B,H,64,4096) bf16; attns (B,64,4096) fp32.
// ---------------------------------------------------------------------------
__global__ __launch_bounds__(256) void smstats_k(
    const u16* __restrict__ S, float2* __restrict__ stats,
    float* __restrict__ attns)
{
    const int bq = blockIdx.x;
    const int b = bq >> 6, q = bq & 63;
    const int t = threadIdx.x;
    const int w = t >> 6, lane = t & 63;
    __shared__ float red[4];
    const int kb = t * 16;

    float attnacc[16];
#pragma unroll
    for (int j = 0; j < 16; ++j) attnacc[j] = 0.f;

    for (int h = 0; h < 8; ++h) {
        const long roff = (((long)(b * 8 + h)) * 64 + q) * 4096;
        const u16* Srow = S + roff;
        float v[16];
        short8 s0 = *(const short8*)(Srow + kb);
        short8 s1 = *(const short8*)(Srow + kb + 8);
#pragma unroll
        for (int j = 0; j < 8; ++j) { v[j] = b2f((u16)s0[j]); v[8 + j] = b2f((u16)s1[j]); }

        float m = -3.0e38f;
#pragma unroll
        for (int j = 0; j < 16; ++j) m = fmaxf(m, v[j]);
        m = waveMax(m);
        __syncthreads();
        if (lane == 0) red[w] = m;
        __syncthreads();
        m = fmaxf(fmaxf(red[0], red[1]), fmaxf(red[2], red[3]));

        float s = 0.f;
#pragma unroll
        for (int j = 0; j < 16; ++j) s += __expf(v[j] - m);
        s = waveSum(s);
        __syncthreads();
        if (lane == 0) red[w] = s;
        __syncthreads();
        s = red[0] + red[1] + red[2] + red[3];

        if (t == 0) stats[(b * 8 + h) * 64 + q] = make_float2(m, 1.f / s);
#pragma unroll
        for (int j = 0; j < 16; ++j) attnacc[j] += v[j];
    }
    float* arow = attns + (long)bq * 4096;
#pragma unroll
    for (int j = 0; j < 16; ++j) arow[kb + j] = attnacc[j] * 0.125f;  // /H
}

// ---------------------------------------------------------------------------
// split-K PV reduce: part (8,128,64,64) fp32 -> o16 (16,64,512) bf16
// ---------------------------------------------------------------------------
__global__ __launch_bounds__(256) void pv_reduce_k(
    const float* __restrict__ part, u16* __restrict__ o16)
{
    const int i = blockIdx.x * 256 + threadIdx.x;   // 131072 threads x 4 elems
    const int d4 = i & 15;
    const int q  = (i >> 4) & 63;
    const int bh = i >> 10;                          // 0..127
    const float* p = part + (long)bh * 4096 + q * 64 + d4 * 4;
    float4 s = {0.f, 0.f, 0.f, 0.f};
#pragma unroll
    for (int sp = 0; sp < 8; ++sp) {
        const float4 v = *(const float4*)(p + (long)sp * 524288);
        s.x += v.x; s.y += v.y; s.z += v.z; s.w += v.w;
    }
    const int b = bh >> 3, h = bh & 7;
    u16* o = o16 + (long)b * 32768 + q * 512 + h * 64 + d4 * 4;
    short4v r;
    r[0] = (short)f2b(s.x); r[1] = (short)f2b(s.y);
    r[2] = (short)f2b(s.z); r[3] = (short)f2b(s.w);
    *(short4v*)o = r;
}

// split-K FF2 reduce + bias: part (4,1024,512) fp32 -> out (1024,512) fp32
__global__ __launch_bounds__(256) void ffred_k(
    const float* __restrict__ part, const float* __restrict__ bias,
    float* __restrict__ out)
{
    const int i = (blockIdx.x * 256 + threadIdx.x) * 4;  // grid 512
    const int c = i & 511;
    float4 s = *(const float4*)(part + i);
#pragma unroll
    for (int sp = 1; sp < 4; ++sp) {
        const float4 v = *(const float4*)(part + (long)sp * 524288 + i);
        s.x += v.x; s.y += v.y; s.z += v.z; s.w += v.w;
    }
    s.x += bias[c]; s.y += bias[c + 1]; s.z += bias[c + 2]; s.w += bias[c + 3];
    *(float4*)(out + i) = s;
}

// ---------------------------------------------------------------------------
// u[l][b][c'] = sum_c Wk[l][c'][c] * extra[b][c]   (for the aff gate)
// ---------------------------------------------------------------------------
__global__ __launch_bounds__(256) void umat_k(
    const float* __restrict__ Wk, const float* __restrict__ extra,
    float* __restrict__ u)
{
    __shared__ float ex[16][512];
    const int l = blockIdx.x;
    const int t = threadIdx.x;
    for (int i = t; i < 16 * 512 / 4; i += 256)
        ((float4*)&ex[0][0])[i] = ((const float4*)extra)[i];
    __syncthreads();
    const int lane = t & 63, wave = t >> 6;
    const int row = blockIdx.y * 4 + wave;          // c' in [0,512)
    const float* wrow = Wk + ((size_t)l * 512 + row) * 512 + lane * 8;
    float w[8];
#pragma unroll
    for (int j = 0; j < 8; ++j) w[j] = wrow[j];
    float s[16];
#pragma unroll
    for (int b = 0; b < 16; ++b) {
        float x = 0.f;
#pragma unroll
        for (int j = 0; j < 8; ++j) x += w[j] * ex[b][lane * 8 + j];
        s[b] = waveSum(x);
    }
    if (lane < 16) u[((size_t)l * 16 + lane) * 512 + row] = s[lane];
}

// cb[l*16+b] = dot(extra[b], bk[l])
__global__ __launch_bounds__(256) void cbk_k(
    const float* __restrict__ bk, const float* __restrict__ extra,
    float* __restrict__ cb)
{
    const int gw = blockIdx.x * 4 + (threadIdx.x >> 6);  // 48 waves
    const int lane = threadIdx.x & 63;
    const int l = gw >> 4, b = gw & 15;
    float s = 0.f;
#pragma unroll
    for (int j = 0; j < 8; ++j)
        s += extra[b * 512 + lane * 8 + j] * bk[l * 512 + lane * 8 + j];
    s = waveSum(s);
    if (lane == 0) cb[gw] = s;
}

// ---------------------------------------------------------------------------
// feat fp32 -> bf16, fused with aff for all 3 layers:
// aff[l][b][k] = sigmoid(SCALE/H * (feat[b,k,:]·u[l][b] + cb[l][b]))
// ---------------------------------------------------------------------------
__global__ __launch_bounds__(256) void cvt16_aff_k(
    const float* __restrict__ feat, u16* __restrict__ dst,
    const float* __restrict__ u, const float* __restrict__ cb,
    float* __restrict__ affb, float* __restrict__ affs_out)
{
    const int t = blockIdx.x * 256 + threadIdx.x;
    const long i = (long)t * 8;
    const int lane = threadIdx.x & 63;
    const int r = t >> 6;           // row (b*4096 + k)
    const int b = r >> 12;
    const float4 a0 = *(const float4*)(feat + i);
    const float4 a1 = *(const float4*)(feat + i + 4);
    short8 o;
    o[0] = (short)f2b(a0.x); o[1] = (short)f2b(a0.y);
    o[2] = (short)f2b(a0.z); o[3] = (short)f2b(a0.w);
    o[4] = (short)f2b(a1.x); o[5] = (short)f2b(a1.y);
    o[6] = (short)f2b(a1.z); o[7] = (short)f2b(a1.w);
    *(short8*)(dst + i) = o;
    const float f[8] = {a0.x, a0.y, a0.z, a0.w, a1.x, a1.y, a1.z, a1.w};
#pragma unroll
    for (int l = 0; l < 3; ++l) {
        const float* ur = u + ((size_t)l * 16 + b) * 512 + lane * 8;
        float s = 0.f;
#pragma unroll
        for (int j = 0; j < 8; ++j) s += f[j] * ur[j];
        s = waveSum(s);
        if (lane == 0) {
            const float av = 1.f / (1.f + __expf(-0.015625f * (s + cb[l * 16 + b])));
            affb[l * 65536 + r] = av;
            affs_out[l * 65536 + r] = av;
        }
    }
}

// ---------------------------------------------------------------------------
// x = LN(x + add; g, beta); updates x (fp32) and x16 (bf16); optional out copy.
// ---------------------------------------------------------------------------
template<bool WRITE_OUT>
__global__ __launch_bounds__(256) void ln_k(
    float* __restrict__ x, const float* __restrict__ add,
    const float* __restrict__ g, const float* __restrict__ be,
    u16* __restrict__ x16, float* __restrict__ outp)
{
    const int r = blockIdx.x, t = threadIdx.x;
    const int w = t >> 6, lane = t & 63;
    __shared__ float red[4];
    float* xr = x + (long)r * 512;
    const float* ar = add + (long)r * 512;
    const float v0 = xr[2 * t]     + ar[2 * t];
    const float v1 = xr[2 * t + 1] + ar[2 * t + 1];
    float s = waveSum(v0 + v1);
    if (lane == 0) red[w] = s;
    __syncthreads();
    s = red[0] + red[1] + red[2] + red[3];
    const float mu = s * (1.f / 512.f);
    const float d0 = v0 - mu, d1 = v1 - mu;
    __syncthreads();
    float vs = waveSum(d0 * d0 + d1 * d1);
    if (lane == 0) red[w] = vs;
    __syncthreads();
    vs = red[0] + red[1] + red[2] + red[3];
    const float rs = rsqrtf(vs * (1.f / 512.f) + 1e-5f);
    const float o0 = g[2 * t]     * d0 * rs + be[2 * t];
    const float o1 = g[2 * t + 1] * d1 * rs + be[2 * t + 1];
    xr[2 * t] = o0; xr[2 * t + 1] = o1;
    x16[(long)r * 512 + 2 * t]     = f2b(o0);
    x16[(long)r * 512 + 2 * t + 1] = f2b(o1);
    if constexpr (WRITE_OUT) {
        outp[(long)r * 512 + 2 * t]     = o0;
        outp[(long)r * 512 + 2 * t + 1] = o1;
    }
}

// x = copy(queries) fp32 + bf16
__global__ __launch_bounds__(256) void initx_k(
    const float* __restrict__ src, float* __restrict__ x, u16* __restrict__ x16)
{
    const long i = ((long)blockIdx.x * 256 + threadIdx.x) * 8;
    const float4 a = *(const float4*)(src + i);
    const float4 b = *(const float4*)(src + i + 4);
    *(float4*)(x + i) = a;
    *(float4*)(x + i + 4) = b;
    short8 r;
    r[0] = (short)f2b(a.x); r[1] = (short)f2b(a.y); r[2] = (short)f2b(a.z); r[3] = (short)f2b(a.w);
    r[4] = (short)f2b(b.x); r[5] = (short)f2b(b.y); r[6] = (short)f2b(b.z); r[7] = (short)f2b(b.w);
    *(short8*)(x16 + i) = r;
}

// W (K,N) fp32 -> WT (N,K) bf16, batched over blockIdx.z
__global__ __launch_bounds__(256) void transpose_w_k(
    const float* __restrict__ W, u16* __restrict__ WT, int K, int N)
{
    __shared__ float tile[32][33];
    const int z = blockIdx.z;
    W  += (size_t)z * K * N;
    WT += (size_t)z * K * N;
    const int n0 = blockIdx.x * 32, k0 = blockIdx.y * 32;
    const int tx = threadIdx.x & 31, ty = threadIdx.x >> 5;
#pragma unroll
    for (int j = 0; j < 32; j += 8)
        tile[ty + j][tx] = W[(size_t)(k0 + ty + j) * N + n0 + tx];
    __syncthreads();
#pragma unroll
    for (int j = 0; j < 32; j += 8)
        WT[(size_t)(n0 + ty + j) * K + k0 + tx] = f2b(tile[tx][ty + j]);
}

// ---------------------------------------------------------------------------
extern "C" void kernel_launch(void* const* d_in, const int* in_sizes, int n_in,
                              void* d_out, int out_size, void* d_ws, size_t ws_size,
                              hipStream_t stream)
{
    (void)in_sizes; (void)n_in; (void)out_size; (void)ws_size;
    const float* queries = (const float*)d_in[0];
    const float* feat    = (const float*)d_in[1];
    const float* extra   = (const float*)d_in[2];
    const float* Wq = (const float*)d_in[3];  const float* bq = (const float*)d_in[4];
    const float* Wk = (const float*)d_in[5];  const float* bk = (const float*)d_in[6];
    const float* Wv = (const float*)d_in[7];  const float* bv = (const float*)d_in[8];
    const float* Wo = (const float*)d_in[9];  const float* bo = (const float*)d_in[10];
    const float* W1 = (const float*)d_in[11]; const float* b1 = (const float*)d_in[12];
    const float* W2 = (const float*)d_in[13]; const float* b2 = (const float*)d_in[14];
    const float* g2 = (const float*)d_in[15]; const float* be2 = (const float*)d_in[16];
    const float* g3 = (const float*)d_in[17]; const float* be3 = (const float*)d_in[18];

    char* wsb = (char*)d_ws;
    size_t off = 0;
    auto alloc = [&](size_t bytes) -> char* {
        char* p = wsb + off; off += (bytes + 255) & ~(size_t)255; return p;
    };
    u16*  feat16 = (u16*)alloc(33554432ull * 2);   // (B*Nk, C) bf16
    u16*  WqT = (u16*)alloc(786432ull * 2);        // (L,512,512) transposed
    u16*  WkT = (u16*)alloc(786432ull * 2);
    u16*  WvT = (u16*)alloc(786432ull * 2);
    u16*  WoT = (u16*)alloc(786432ull * 2);
    u16*  W1T = (u16*)alloc(3145728ull * 2);       // (L,2048,512)
    u16*  W2T = (u16*)alloc(3145728ull * 2);       // (L,512,2048)
    u16*  K16 = (u16*)alloc(33554432ull * 2);      // (B,Nk,C); later PV partials
    u16*  VT16 = (u16*)alloc(33554432ull * 2);     // (B,C,Nk) aff-gated; later FF2 partials
    u16*  q16 = (u16*)alloc(524288ull * 2);        // (B*Nq, C)
    u16*  S16 = (u16*)alloc(33554432ull * 2);      // (B,H,64,4096) scores*SCALE
    float* affb  = (float*)alloc(196608ull * 4);   // (L,B,Nk)
    u16*  o16 = (u16*)alloc(524288ull * 2);        // attention out (B,Nq,C)
    float* oproj = (float*)alloc(524288ull * 4);
    float* xb    = (float*)alloc(524288ull * 4);
    u16*  x16 = (u16*)alloc(524288ull * 2);
    u16*  h116 = (u16*)alloc(2097152ull * 2);      // (B*Nq, 2048)
    float* ffb   = (float*)alloc(524288ull * 4);
    float* uvec  = (float*)alloc(24576ull * 4);    // (L,16,512)
    float* cb    = (float*)alloc(48ull * 4);
    float2* stats = (float2*)alloc(8192ull * 8);   // (B*H*64) {m, 1/sum}
    float* partPV = (float*)K16;                   // alias: K dead after S-GEMM
    float* part2  = (float*)VT16;                  // alias: VT dead after PV

    float* out_f = (float*)d_out;
    float* outs_base  = out_f;                     // (3,16,64,512)
    float* attns_base = out_f + 1572864;           // (3,16,64,4096)
    float* affs_base  = out_f + 14155776;          // (3,16,1,1,4096)

    // prep (layer-independent)
    umat_k<<<dim3(3, 128), 256, 0, stream>>>(Wk, extra, uvec);
    cbk_k<<<12, 256, 0, stream>>>(bk, extra, cb);
    cvt16_aff_k<<<16384, 256, 0, stream>>>(feat, feat16, uvec, cb, affb, affs_base);
    initx_k<<<256, 256, 0, stream>>>(queries, xb, x16);
    transpose_w_k<<<dim3(16, 16, 3), 256, 0, stream>>>(Wq, WqT, 512, 512);
    transpose_w_k<<<dim3(16, 16, 3), 256, 0, stream>>>(Wk, WkT, 512, 512);
    transpose_w_k<<<dim3(16, 16, 3), 256, 0, stream>>>(Wv, WvT, 512, 512);
    transpose_w_k<<<dim3(16, 16, 3), 256, 0, stream>>>(Wo, WoT, 512, 512);
    transpose_w_k<<<dim3(64, 16, 3), 256, 0, stream>>>(W1, W1T, 512, 2048);
    transpose_w_k<<<dim3(16, 64, 3), 256, 0, stream>>>(W2, W2T, 2048, 512);

    for (int i = 0; i < 3; ++i) {
        // K = feat @ Wk + bk   (M=65536, N=512, K=512) -> bf16 (B,Nk,C)
        gemm_bt_k<128, 128, true, false, false, true, false, false>
            <<<dim3(4, 512, 1), 256, 0, stream>>>(
            feat16, WkT + i * 262144, bk + i * 512, K16,
            512, 512, 512, 512, 1, 0, 0, 0, 0, 0, 0, 1.f, nullptr, nullptr);
        // VT'[b] = aff ⊙ ((feat[b] @ Wv)^T + bv)  -> (B,C,Nk)
        gemm_bt_k<128, 128, true, false, true, true, true, false>
            <<<dim3(32, 4, 16), 256, 0, stream>>>(
            WvT + i * 262144, feat16, bv + i * 512, VT16,
            512, 512, 512, 4096, 1, 0, 0, 2097152, 0, 2097152, 0, 1.f,
            affb + i * 65536, nullptr);
        // q = x @ Wq + bq  (1024 x 512)
        gemm_bt_k<64, 64, true, false, false, true, false, false>
            <<<dim3(8, 16, 1), 256, 0, stream>>>(
            x16, WqT + i * 262144, bq + i * 512, q16,
            512, 512, 512, 512, 1, 0, 0, 0, 0, 0, 0, 1.f, nullptr, nullptr);
        // S[b,h] = SCALE * q_h @ K_h^T   (batch 128: M=64,N=4096,K=64)
        gemm_bt_k<64, 128, true, false, false, false, false, false>
            <<<dim3(32, 1, 128), 256, 0, stream>>>(
            q16, K16, nullptr, S16,
            64, 512, 512, 4096, 8, 32768, 64, 2097152, 64, 2097152, 262144,
            0.125f, nullptr, nullptr);
        // softmax stats + attns
        smstats_k<<<1024, 256, 0, stream>>>(
            S16, stats, attns_base + (size_t)i * 4194304);
        // o[b,h] = softmax(S) @ V', split-K 8, softmax fused at fragment load
        gemm_bt_k<64, 64, false, false, false, false, false, true>
            <<<dim3(1, 1, 1024), 256, 0, stream>>>(
            S16, VT16, nullptr, partPV,
            512, 4096, 4096, 64, 128, 512, 262144, 512, 262144, 524288, 4096,
            1.f, nullptr, stats);
        pv_reduce_k<<<512, 256, 0, stream>>>(partPV, o16);
        // o @ Wo + bo -> fp32
        gemm_bt_k<64, 64, false, false, false, true, false, false>
            <<<dim3(8, 16, 1), 256, 0, stream>>>(
            o16, WoT + i * 262144, bo + i * 512, oproj,
            512, 512, 512, 512, 1, 0, 0, 0, 0, 0, 0, 1.f, nullptr, nullptr);
        // x = LN(x + oproj; g2, beta2)
        ln_k<false><<<1024, 256, 0, stream>>>(xb, oproj, g2 + i * 512, be2 + i * 512, x16, nullptr);
        // h1 = relu(x @ W1 + b1) -> bf16 (1024 x 2048)
        gemm_bt_k<64, 128, true, true, false, true, false, false>
            <<<dim3(16, 16, 1), 256, 0, stream>>>(
            x16, W1T + (size_t)i * 1048576, b1 + i * 2048, h116,
            512, 512, 512, 2048, 1, 0, 0, 0, 0, 0, 0, 1.f, nullptr, nullptr);
        // ff partials = h1 @ W2 (split-K 4) -> fp32 (4,1024,512)
        gemm_bt_k<64, 64, false, false, false, false, false, false>
            <<<dim3(8, 16, 4), 256, 0, stream>>>(
            h116, W2T + (size_t)i * 1048576, nullptr, part2,
            512, 2048, 2048, 512, 1, 512, 0, 512, 0, 524288, 0,
            1.f, nullptr, nullptr);
        ffred_k<<<512, 256, 0, stream>>>(part2, b2 + i * 512, ffb);
        // x = LN(x + ff; g3, beta3), write outs[i]
        ln_k<true><<<1024, 256, 0, stream>>>(xb, ffb, g3 + i * 512, be3 + i * 512, x16,
                                             outs_base + (size_t)i * 524288);
    }
}

// Round 6
// 847.801 us; speedup vs baseline: 1.3155x; 1.0007x over previous
//
#include <hip/hip_runtime.h>

// SegDecoder: 3-layer cross-attention decoder on MI355X (gfx950).
// B=16, Nq=64, Nk=4096, C=512, H=8, hd=64, FF=2048, L=3.
// R6: BK=32 double-buffered 2-phase GEMM loop (stage-next BEFORE compute-cur,
// ONE vmcnt(0)+barrier per K-step == __syncthreads; 32KB LDS keeps 5 blk/CU).
// XCD swizzle removed (L3-fit regime, measured neutral-negative in R5).

typedef unsigned short u16;
typedef __attribute__((ext_vector_type(8))) short short8;
typedef __attribute__((ext_vector_type(4))) short short4v;
typedef __attribute__((ext_vector_type(4))) float f32x4;

__device__ __forceinline__ float b2f(u16 u) {
    union { unsigned int i; float f; } v; v.i = ((unsigned int)u) << 16; return v.f;
}
__device__ __forceinline__ u16 f2b(float f) {  // round-to-nearest-even
    unsigned int x = __float_as_uint(f);
    x += 0x7fffu + ((x >> 16) & 1u);
    return (u16)(x >> 16);
}

__device__ __forceinline__ float waveSum(float v) {
#pragma unroll
    for (int o = 32; o > 0; o >>= 1) v += __shfl_xor(v, o);
    return v;
}
__device__ __forceinline__ float waveMax(float v) {
#pragma unroll
    for (int o = 32; o > 0; o >>= 1) v = fmaxf(v, __shfl_xor(v, o));
    return v;
}

// async global->LDS, 16B per lane. LDS dest is wave-uniform base + lane*16.
__device__ __forceinline__ void gl_lds16(const void* g, void* l) {
    __builtin_amdgcn_global_load_lds(
        (__attribute__((address_space(1))) void*)g,
        (__attribute__((address_space(3))) void*)l, 16, 0, 0);
}

// ---------------------------------------------------------------------------
// Generic batched GEMM:  C = alpha * A(M,K) @ Bt(N,K)^T [+ bias][*affc][relu]
// BK=32 rows of 64B (4 x 16B units), unit swizzle u^((row>>1)&3) (R2-proven,
// 0 conflicts). Double-buffered LDS (32KB for 128x128) with the verified
// 2-phase recipe: stage(next) issued BEFORE compute(cur); one
// __syncthreads (vmcnt(0)+lgkmcnt(0)+s_barrier) per K-step.
// SMAX: A holds bf16 scores s; fragment transform p=exp(s-m)*inv from stats.
// AFFC: epilogue *= affc[zq*4096 + col].
// ---------------------------------------------------------------------------
template<int TM, int TN, bool OUT_BF16, bool RELU, bool BIAS_ROW, bool HAS_BIAS,
         bool AFFC, bool SMAX>
__global__ __launch_bounds__(256) void gemm_bt_k(
    const u16* __restrict__ A, const u16* __restrict__ Bt,
    const float* __restrict__ bias, void* __restrict__ Cout,
    int K, int lda, int ldb, int ldc,
    int bdiv, long sA1, long sA2, long sB1, long sB2, long sC1, long sC2,
    float alpha, const float* __restrict__ affc, const float2* __restrict__ stats)
{
    __shared__ u16 As[2][TM][32];
    __shared__ u16 Bs[2][TN][32];
    const int t = threadIdx.x;
    const int lane = t & 63;
    const int wave = t >> 6;
    const int z = blockIdx.z;
    const int zq = z / bdiv, zr = z % bdiv;
    A  += (long)zq * sA1 + (long)zr * sA2;
    Bt += (long)zq * sB1 + (long)zr * sB2;
    const long cbase = (long)zq * sC1 + (long)zr * sC2;
    const int n0 = blockIdx.x * TN;
    const int m0 = blockIdx.y * TM;
    constexpr int FM = TM / 32, FN = TN / 32;
    const int wr = wave >> 1, wc = wave & 1;
    const int rl = lane & 15, uq = lane >> 4;

    float2 st[FM];
    if constexpr (SMAX) {
#pragma unroll
        for (int i = 0; i < FM; ++i)
            st[i] = stats[zr * 64 + m0 + wr * (TM / 2) + i * 16 + rl];
    }

    f32x4 acc[FM][FN];
#pragma unroll
    for (int i = 0; i < FM; ++i)
#pragma unroll
        for (int j = 0; j < FN; ++j) acc[i][j] = (f32x4){0.f, 0.f, 0.f, 0.f};

    // staging: one issue = 16 rows x 64B = 1KB; srow in [0,16), up = 16B unit
    const int srow = lane >> 2;
    const int up   = lane & 3;

    auto stage = [&](int buf, int k0) {
#pragma unroll
        for (int r = 0; r < TM / 64; ++r) {
            const int br = (wave * (TM / 64) + r) * 16;
            const int row = br + srow;
            const int ul = up ^ ((row >> 1) & 3);
            gl_lds16(A + (long)(m0 + row) * lda + k0 + ul * 8, &As[buf][br][0]);
        }
#pragma unroll
        for (int r = 0; r < TN / 64; ++r) {
            const int br = (wave * (TN / 64) + r) * 16;
            const int row = br + srow;
            const int ul = up ^ ((row >> 1) & 3);
            gl_lds16(Bt + (long)(n0 + row) * ldb + k0 + ul * 8, &Bs[buf][br][0]);
        }
    };

    auto compute = [&](int buf) {
        short8 af[FM], bf[FN];
#pragma unroll
        for (int i = 0; i < FM; ++i) {
            const int R = wr * (TM / 2) + i * 16 + rl;
            af[i] = *(const short8*)(&As[buf][R][(uq ^ ((R >> 1) & 3)) * 8]);
            if constexpr (SMAX) {
#pragma unroll
                for (int e = 0; e < 8; ++e)
                    af[i][e] = (short)f2b(
                        __expf(b2f((u16)af[i][e]) - st[i].x) * st[i].y);
            }
        }
#pragma unroll
        for (int j = 0; j < FN; ++j) {
            const int R = wc * (TN / 2) + j * 16 + rl;
            bf[j] = *(const short8*)(&Bs[buf][R][(uq ^ ((R >> 1) & 3)) * 8]);
        }
#pragma unroll
        for (int i = 0; i < FM; ++i)
#pragma unroll
            for (int j = 0; j < FN; ++j)
                acc[i][j] = __builtin_amdgcn_mfma_f32_16x16x32_bf16(
                    af[i], bf[j], acc[i][j], 0, 0, 0);
    };

    // 2-phase: stage(next) BEFORE compute(cur); one barrier per K-step.
    stage(0, 0);
    __syncthreads();                 // drain prologue stage
    const int NT = K >> 5;
    int cur = 0;
    for (int kt = 0; kt < NT; ++kt) {
        if (kt + 1 < NT) stage(cur ^ 1, (kt + 1) * 32);
        compute(cur);
        __syncthreads();             // vmcnt(0): stage(kt+1) landed; barrier
        cur ^= 1;
    }

    const int r0 = (lane >> 4) * 4;
    const int c0 = lane & 15;
#pragma unroll
    for (int i = 0; i < FM; ++i) {
#pragma unroll
        for (int j = 0; j < FN; ++j) {
#pragma unroll
            for (int r = 0; r < 4; ++r) {
                const int row = m0 + wr * (TM / 2) + i * 16 + r0 + r;
                const int col = n0 + wc * (TN / 2) + j * 16 + c0;
                float v = acc[i][j][r] * alpha;
                if constexpr (HAS_BIAS) {
                    if constexpr (BIAS_ROW) v += bias[row]; else v += bias[col];
                }
                if constexpr (AFFC) v *= affc[(long)zq * 4096 + col];
                if constexpr (RELU) v = fmaxf(v, 0.f);
                const long idx = cbase + (long)row * ldc + col;
                if constexpr (OUT_BF16) ((u16*)Cout)[idx] = f2b(v);
                else                    ((float*)Cout)[idx] = v;
            }
        }
    }
}

// ---------------------------------------------------------------------------
// softmax stats (m, 1/sum) per (b,h,q) + head-averaged score output.
// block = (b,q); S layout (B,H,64,4096) bf16; attns (B,64,4096) fp32.
// ---------------------------------------------------------------------------
__global__ __launch_bounds__(256) void smstats_k(
    const u16* __restrict__ S, float2* __restrict__ stats,
    float* __restrict__ attns)
{
    const int bq = blockIdx.x;
    const int b = bq >> 6, q = bq & 63;
    const int t = threadIdx.x;
    const int w = t >> 6, lane = t & 63;
    __shared__ float red[4];
    const int kb = t * 16;

    float attnacc[16];
#pragma unroll
    for (int j = 0; j < 16; ++j) attnacc[j] = 0.f;

    for (int h = 0; h < 8; ++h) {
        const long roff = (((long)(b * 8 + h)) * 64 + q) * 4096;
        const u16* Srow = S + roff;
        float v[16];
        short8 s0 = *(const short8*)(Srow + kb);
        short8 s1 = *(const short8*)(Srow + kb + 8);
#pragma unroll
        for (int j = 0; j < 8; ++j) { v[j] = b2f((u16)s0[j]); v[8 + j] = b2f((u16)s1[j]); }

        float m = -3.0e38f;
#pragma unroll
        for (int j = 0; j < 16; ++j) m = fmaxf(m, v[j]);
        m = waveMax(m);
        __syncthreads();
        if (lane == 0) red[w] = m;
        __syncthreads();
        m = fmaxf(fmaxf(red[0], red[1]), fmaxf(red[2], red[3]));

        float s = 0.f;
#pragma unroll
        for (int j = 0; j < 16; ++j) s += __expf(v[j] - m);
        s = waveSum(s);
        __syncthreads();
        if (lane == 0) red[w] = s;
        __syncthreads();
        s = red[0] + red[1] + red[2] + red[3];

        if (t == 0) stats[(b * 8 + h) * 64 + q] = make_float2(m, 1.f / s);
#pragma unroll
        for (int j = 0; j < 16; ++j) attnacc[j] += v[j];
    }
    float* arow = attns + (long)bq * 4096;
#pragma unroll
    for (int j = 0; j < 16; ++j) arow[kb + j] = attnacc[j] * 0.125f;  // /H
}

// ---------------------------------------------------------------------------
// split-K PV reduce: part (8,128,64,64) fp32 -> o16 (16,64,512) bf16
// ---------------------------------------------------------------------------
__global__ __launch_bounds__(256) void pv_reduce_k(
    const float* __restrict__ part, u16* __restrict__ o16)
{
    const int i = blockIdx.x * 256 + threadIdx.x;   // 131072 threads x 4 elems
    const int d4 = i & 15;
    const int q  = (i >> 4) & 63;
    const int bh = i >> 10;                          // 0..127
    const float* p = part + (long)bh * 4096 + q * 64 + d4 * 4;
    float4 s = {0.f, 0.f, 0.f, 0.f};
#pragma unroll
    for (int sp = 0; sp < 8; ++sp) {
        const float4 v = *(const float4*)(p + (long)sp * 524288);
        s.x += v.x; s.y += v.y; s.z += v.z; s.w += v.w;
    }
    const int b = bh >> 3, h = bh & 7;
    u16* o = o16 + (long)b * 32768 + q * 512 + h * 64 + d4 * 4;
    short4v r;
    r[0] = (short)f2b(s.x); r[1] = (short)f2b(s.y);
    r[2] = (short)f2b(s.z); r[3] = (short)f2b(s.w);
    *(short4v*)o = r;
}

// split-K FF2 reduce + bias: part (4,1024,512) fp32 -> out (1024,512) fp32
__global__ __launch_bounds__(256) void ffred_k(
    const float* __restrict__ part, const float* __restrict__ bias,
    float* __restrict__ out)
{
    const int i = (blockIdx.x * 256 + threadIdx.x) * 4;  // grid 512
    const int c = i & 511;
    float4 s = *(const float4*)(part + i);
#pragma unroll
    for (int sp = 1; sp < 4; ++sp) {
        const float4 v = *(const float4*)(part + (long)sp * 524288 + i);
        s.x += v.x; s.y += v.y; s.z += v.z; s.w += v.w;
    }
    s.x += bias[c]; s.y += bias[c + 1]; s.z += bias[c + 2]; s.w += bias[c + 3];
    *(float4*)(out + i) = s;
}

// ---------------------------------------------------------------------------
// u[l][b][c'] = sum_c Wk[l][c'][c] * extra[b][c]   (for the aff gate)
// ---------------------------------------------------------------------------
__global__ __launch_bounds__(256) void umat_k(
    const float* __restrict__ Wk, const float* __restrict__ extra,
    float* __restrict__ u)
{
    __shared__ float ex[16][512];
    const int l = blockIdx.x;
    const int t = threadIdx.x;
    for (int i = t; i < 16 * 512 / 4; i += 256)
        ((float4*)&ex[0][0])[i] = ((const float4*)extra)[i];
    __syncthreads();
    const int lane = t & 63, wave = t >> 6;
    const int row = blockIdx.y * 4 + wave;          // c' in [0,512)
    const float* wrow = Wk + ((size_t)l * 512 + row) * 512 + lane * 8;
    float w[8];
#pragma unroll
    for (int j = 0; j < 8; ++j) w[j] = wrow[j];
    float s[16];
#pragma unroll
    for (int b = 0; b < 16; ++b) {
        float x = 0.f;
#pragma unroll
        for (int j = 0; j < 8; ++j) x += w[j] * ex[b][lane * 8 + j];
        s[b] = waveSum(x);
    }
    if (lane < 16) u[((size_t)l * 16 + lane) * 512 + row] = s[lane];
}

// cb[l*16+b] = dot(extra[b], bk[l])
__global__ __launch_bounds__(256) void cbk_k(
    const float* __restrict__ bk, const float* __restrict__ extra,
    float* __restrict__ cb)
{
    const int gw = blockIdx.x * 4 + (threadIdx.x >> 6);  // 48 waves
    const int lane = threadIdx.x & 63;
    const int l = gw >> 4, b = gw & 15;
    float s = 0.f;
#pragma unroll
    for (int j = 0; j < 8; ++j)
        s += extra[b * 512 + lane * 8 + j] * bk[l * 512 + lane * 8 + j];
    s = waveSum(s);
    if (lane == 0) cb[gw] = s;
}

// ---------------------------------------------------------------------------
// feat fp32 -> bf16, fused with aff for all 3 layers:
// aff[l][b][k] = sigmoid(SCALE/H * (feat[b,k,:]·u[l][b] + cb[l][b]))
// ---------------------------------------------------------------------------
__global__ __launch_bounds__(256) void cvt16_aff_k(
    const float* __restrict__ feat, u16* __restrict__ dst,
    const float* __restrict__ u, const float* __restrict__ cb,
    float* __restrict__ affb, float* __restrict__ affs_out)
{
    const int t = blockIdx.x * 256 + threadIdx.x;
    const long i = (long)t * 8;
    const int lane = threadIdx.x & 63;
    const int r = t >> 6;           // row (b*4096 + k)
    const int b = r >> 12;
    const float4 a0 = *(const float4*)(feat + i);
    const float4 a1 = *(const float4*)(feat + i + 4);
    short8 o;
    o[0] = (short)f2b(a0.x); o[1] = (short)f2b(a0.y);
    o[2] = (short)f2b(a0.z); o[3] = (short)f2b(a0.w);
    o[4] = (short)f2b(a1.x); o[5] = (short)f2b(a1.y);
    o[6] = (short)f2b(a1.z); o[7] = (short)f2b(a1.w);
    *(short8*)(dst + i) = o;
    const float f[8] = {a0.x, a0.y, a0.z, a0.w, a1.x, a1.y, a1.z, a1.w};
#pragma unroll
    for (int l = 0; l < 3; ++l) {
        const float* ur = u + ((size_t)l * 16 + b) * 512 + lane * 8;
        float s = 0.f;
#pragma unroll
        for (int j = 0; j < 8; ++j) s += f[j] * ur[j];
        s = waveSum(s);
        if (lane == 0) {
            const float av = 1.f / (1.f + __expf(-0.015625f * (s + cb[l * 16 + b])));
            affb[l * 65536 + r] = av;
            affs_out[l * 65536 + r] = av;
        }
    }
}

// ---------------------------------------------------------------------------
// x = LN(x + add; g, beta); updates x (fp32) and x16 (bf16); optional out copy.
// ---------------------------------------------------------------------------
template<bool WRITE_OUT>
__global__ __launch_bounds__(256) void ln_k(
    float* __restrict__ x, const float* __restrict__ add,
    const float* __restrict__ g, const float* __restrict__ be,
    u16* __restrict__ x16, float* __restrict__ outp)
{
    const int r = blockIdx.x, t = threadIdx.x;
    const int w = t >> 6, lane = t & 63;
    __shared__ float red[4];
    float* xr = x + (long)r * 512;
    const float* ar = add + (long)r * 512;
    const float v0 = xr[2 * t]     + ar[2 * t];
    const float v1 = xr[2 * t + 1] + ar[2 * t + 1];
    float s = waveSum(v0 + v1);
    if (lane == 0) red[w] = s;
    __syncthreads();
    s = red[0] + red[1] + red[2] + red[3];
    const float mu = s * (1.f / 512.f);
    const float d0 = v0 - mu, d1 = v1 - mu;
    __syncthreads();
    float vs = waveSum(d0 * d0 + d1 * d1);
    if (lane == 0) red[w] = vs;
    __syncthreads();
    vs = red[0] + red[1] + red[2] + red[3];
    const float rs = rsqrtf(vs * (1.f / 512.f) + 1e-5f);
    const float o0 = g[2 * t]     * d0 * rs + be[2 * t];
    const float o1 = g[2 * t + 1] * d1 * rs + be[2 * t + 1];
    xr[2 * t] = o0; xr[2 * t + 1] = o1;
    x16[(long)r * 512 + 2 * t]     = f2b(o0);
    x16[(long)r * 512 + 2 * t + 1] = f2b(o1);
    if constexpr (WRITE_OUT) {
        outp[(long)r * 512 + 2 * t]     = o0;
        outp[(long)r * 512 + 2 * t + 1] = o1;
    }
}

// x = copy(queries) fp32 + bf16
__global__ __launch_bounds__(256) void initx_k(
    const float* __restrict__ src, float* __restrict__ x, u16* __restrict__ x16)
{
    const long i = ((long)blockIdx.x * 256 + threadIdx.x) * 8;
    const float4 a = *(const float4*)(src + i);
    const float4 b = *(const float4*)(src + i + 4);
    *(float4*)(x + i) = a;
    *(float4*)(x + i + 4) = b;
    short8 r;
    r[0] = (short)f2b(a.x); r[1] = (short)f2b(a.y); r[2] = (short)f2b(a.z); r[3] = (short)f2b(a.w);
    r[4] = (short)f2b(b.x); r[5] = (short)f2b(b.y); r[6] = (short)f2b(b.z); r[7] = (short)f2b(b.w);
    *(short8*)(x16 + i) = r;
}

// W (K,N) fp32 -> WT (N,K) bf16, batched over blockIdx.z
__global__ __launch_bounds__(256) void transpose_w_k(
    const float* __restrict__ W, u16* __restrict__ WT, int K, int N)
{
    __shared__ float tile[32][33];
    const int z = blockIdx.z;
    W  += (size_t)z * K * N;
    WT += (size_t)z * K * N;
    const int n0 = blockIdx.x * 32, k0 = blockIdx.y * 32;
    const int tx = threadIdx.x & 31, ty = threadIdx.x >> 5;
#pragma unroll
    for (int j = 0; j < 32; j += 8)
        tile[ty + j][tx] = W[(size_t)(k0 + ty + j) * N + n0 + tx];
    __syncthreads();
#pragma unroll
    for (int j = 0; j < 32; j += 8)
        WT[(size_t)(n0 + ty + j) * K + k0 + tx] = f2b(tile[tx][ty + j]);
}

// ---------------------------------------------------------------------------
extern "C" void kernel_launch(void* const* d_in, const int* in_sizes, int n_in,
                              void* d_out, int out_size, void* d_ws, size_t ws_size,
                              hipStream_t stream)
{
    (void)in_sizes; (void)n_in; (void)out_size; (void)ws_size;
    const float* queries = (const float*)d_in[0];
    const float* feat    = (const float*)d_in[1];
    const float* extra   = (const float*)d_in[2];
    const float* Wq = (const float*)d_in[3];  const float* bq = (const float*)d_in[4];
    const float* Wk = (const float*)d_in[5];  const float* bk = (const float*)d_in[6];
    const float* Wv = (const float*)d_in[7];  const float* bv = (const float*)d_in[8];
    const float* Wo = (const float*)d_in[9];  const float* bo = (const float*)d_in[10];
    const float* W1 = (const float*)d_in[11]; const float* b1 = (const float*)d_in[12];
    const float* W2 = (const float*)d_in[13]; const float* b2 = (const float*)d_in[14];
    const float* g2 = (const float*)d_in[15]; const float* be2 = (const float*)d_in[16];
    const float* g3 = (const float*)d_in[17]; const float* be3 = (const float*)d_in[18];

    char* wsb = (char*)d_ws;
    size_t off = 0;
    auto alloc = [&](size_t bytes) -> char* {
        char* p = wsb + off; off += (bytes + 255) & ~(size_t)255; return p;
    };
    u16*  feat16 = (u16*)alloc(33554432ull * 2);   // (B*Nk, C) bf16
    u16*  WqT = (u16*)alloc(786432ull * 2);        // (L,512,512) transposed
    u16*  WkT = (u16*)alloc(786432ull * 2);
    u16*  WvT = (u16*)alloc(786432ull * 2);
    u16*  WoT = (u16*)alloc(786432ull * 2);
    u16*  W1T = (u16*)alloc(3145728ull * 2);       // (L,2048,512)
    u16*  W2T = (u16*)alloc(3145728ull * 2);       // (L,512,2048)
    u16*  K16 = (u16*)alloc(33554432ull * 2);      // (B,Nk,C); later PV partials
    u16*  VT16 = (u16*)alloc(33554432ull * 2);     // (B,C,Nk) aff-gated; later FF2 partials
    u16*  q16 = (u16*)alloc(524288ull * 2);        // (B*Nq, C)
    u16*  S16 = (u16*)alloc(33554432ull * 2);      // (B,H,64,4096) scores*SCALE
    float* affb  = (float*)alloc(196608ull * 4);   // (L,B,Nk)
    u16*  o16 = (u16*)alloc(524288ull * 2);        // attention out (B,Nq,C)
    float* oproj = (float*)alloc(524288ull * 4);
    float* xb    = (float*)alloc(524288ull * 4);
    u16*  x16 = (u16*)alloc(524288ull * 2);
    u16*  h116 = (u16*)alloc(2097152ull * 2);      // (B*Nq, 2048)
    float* ffb   = (float*)alloc(524288ull * 4);
    float* uvec  = (float*)alloc(24576ull * 4);    // (L,16,512)
    float* cb    = (float*)alloc(48ull * 4);
    float2* stats = (float2*)alloc(8192ull * 8);   // (B*H*64) {m, 1/sum}
    float* partPV = (float*)K16;                   // alias: K dead after S-GEMM
    float* part2  = (float*)VT16;                  // alias: VT dead after PV

    float* out_f = (float*)d_out;
    float* outs_base  = out_f;                     // (3,16,64,512)
    float* attns_base = out_f + 1572864;           // (3,16,64,4096)
    float* affs_base  = out_f + 14155776;          // (3,16,1,1,4096)

    // prep (layer-independent)
    umat_k<<<dim3(3, 128), 256, 0, stream>>>(Wk, extra, uvec);
    cbk_k<<<12, 256, 0, stream>>>(bk, extra, cb);
    cvt16_aff_k<<<16384, 256, 0, stream>>>(feat, feat16, uvec, cb, affb, affs_base);
    initx_k<<<256, 256, 0, stream>>>(queries, xb, x16);
    transpose_w_k<<<dim3(16, 16, 3), 256, 0, stream>>>(Wq, WqT, 512, 512);
    transpose_w_k<<<dim3(16, 16, 3), 256, 0, stream>>>(Wk, WkT, 512, 512);
    transpose_w_k<<<dim3(16, 16, 3), 256, 0, stream>>>(Wv, WvT, 512, 512);
    transpose_w_k<<<dim3(16, 16, 3), 256, 0, stream>>>(Wo, WoT, 512, 512);
    transpose_w_k<<<dim3(64, 16, 3), 256, 0, stream>>>(W1, W1T, 512, 2048);
    transpose_w_k<<<dim3(16, 64, 3), 256, 0, stream>>>(W2, W2T, 2048, 512);

    for (int i = 0; i < 3; ++i) {
        // K = feat @ Wk + bk   (M=65536, N=512, K=512) -> bf16 (B,Nk,C)
        gemm_bt_k<128, 128, true, false, false, true, false, false>
            <<<dim3(4, 512, 1), 256, 0, stream>>>(
            feat16, WkT + i * 262144, bk + i * 512, K16,
            512, 512, 512, 512, 1, 0, 0, 0, 0, 0, 0, 1.f, nullptr, nullptr);
        // VT'[b] = aff ⊙ ((feat[b] @ Wv)^T + bv)  -> (B,C,Nk)
        gemm_bt_k<128, 128, true, false, true, true, true, false>
            <<<dim3(32, 4, 16), 256, 0, stream>>>(
            WvT + i * 262144, feat16, bv + i * 512, VT16,
            512, 512, 512, 4096, 1, 0, 0, 2097152, 0, 2097152, 0, 1.f,
            affb + i * 65536, nullptr);
        // q = x @ Wq + bq  (1024 x 512)
        gemm_bt_k<64, 64, true, false, false, true, false, false>
            <<<dim3(8, 16, 1), 256, 0, stream>>>(
            x16, WqT + i * 262144, bq + i * 512, q16,
            512, 512, 512, 512, 1, 0, 0, 0, 0, 0, 0, 1.f, nullptr, nullptr);
        // S[b,h] = SCALE * q_h @ K_h^T   (batch 128: M=64,N=4096,K=64)
        gemm_bt_k<64, 128, true, false, false, false, false, false>
            <<<dim3(32, 1, 128), 256, 0, stream>>>(
            q16, K16, nullptr, S16,
            64, 512, 512, 4096, 8, 32768, 64, 2097152, 64, 2097152, 262144,
            0.125f, nullptr, nullptr);
        // softmax stats + attns
        smstats_k<<<1024, 256, 0, stream>>>(
            S16, stats, attns_base + (size_t)i * 4194304);
        // o[b,h] = softmax(S) @ V', split-K 8, softmax fused at fragment load
        gemm_bt_k<64, 64, false, false, false, false, false, true>
            <<<dim3(1, 1, 1024), 256, 0, stream>>>(
            S16, VT16, nullptr, partPV,
            512, 4096, 4096, 64, 128, 512, 262144, 512, 262144, 524288, 4096,
            1.f, nullptr, stats);
        pv_reduce_k<<<512, 256, 0, stream>>>(partPV, o16);
        // o @ Wo + bo -> fp32
        gemm_bt_k<64, 64, false, false, false, true, false, false>
            <<<dim3(8, 16, 1), 256, 0, stream>>>(
            o16, WoT + i * 262144, bo + i * 512, oproj,
            512, 512, 512, 512, 1, 0, 0, 0, 0, 0, 0, 1.f, nullptr, nullptr);
        // x = LN(x + oproj; g2, beta2)
        ln_k<false><<<1024, 256, 0, stream>>>(xb, oproj, g2 + i * 512, be2 + i * 512, x16, nullptr);
        // h1 = relu(x @ W1 + b1) -> bf16 (1024 x 2048)
        gemm_bt_k<64, 128, true, true, false, true, false, false>
            <<<dim3(16, 16, 1), 256, 0, stream>>>(
            x16, W1T + (size_t)i * 1048576, b1 + i * 2048, h116,
            512, 512, 512, 2048, 1, 0, 0, 0, 0, 0, 0, 1.f, nullptr, nullptr);
        // ff partials = h1 @ W2 (split-K 4) -> fp32 (4,1024,512)
        gemm_bt_k<64, 64, false, false, false, false, false, false>
            <<<dim3(8, 16, 4), 256, 0, stream>>>(
            h116, W2T + (size_t)i * 1048576, nullptr, part2,
            512, 2048, 2048, 512, 1, 512, 0, 512, 0, 524288, 0,
            1.f, nullptr, nullptr);
        ffred_k<<<512, 256, 0, stream>>>(part2, b2 + i * 512, ffb);
        // x = LN(x + ff; g3, beta3), write outs[i]
        ln_k<true><<<1024, 256, 0, stream>>>(xb, ffb, g3 + i * 512, be3 + i * 512, x16,
                                             outs_base + (size_t)i * 524288);
    }
}

// Round 7
// 816.852 us; speedup vs baseline: 1.3653x; 1.0379x over previous
//
#include <hip/hip_runtime.h>

// SegDecoder: 3-layer cross-attention decoder on MI355X (gfx950).
// B=16, Nq=64, Nk=4096, C=512, H=8, hd=64, FF=2048, L=3.
// R7: Kproj/VT moved to a 256x128-tile BK=64 8-wave TRIPLE-buffered GEMM with
// counted s_waitcnt vmcnt(6) (never 0 in-loop) + raw s_barrier (T4), setprio
// around MFMA cluster (T5). All other GEMMs: R3's best-measured 128^2 BK=64
// single-buffered structure (2-phase/dbuf/XCD-swizzle all measured null).

typedef unsigned short u16;
typedef __attribute__((ext_vector_type(8))) short short8;
typedef __attribute__((ext_vector_type(4))) short short4v;
typedef __attribute__((ext_vector_type(4))) float f32x4;

__device__ __forceinline__ float b2f(u16 u) {
    union { unsigned int i; float f; } v; v.i = ((unsigned int)u) << 16; return v.f;
}
__device__ __forceinline__ u16 f2b(float f) {  // round-to-nearest-even
    unsigned int x = __float_as_uint(f);
    x += 0x7fffu + ((x >> 16) & 1u);
    return (u16)(x >> 16);
}

__device__ __forceinline__ float waveSum(float v) {
#pragma unroll
    for (int o = 32; o > 0; o >>= 1) v += __shfl_xor(v, o);
    return v;
}
__device__ __forceinline__ float waveMax(float v) {
#pragma unroll
    for (int o = 32; o > 0; o >>= 1) v = fmaxf(v, __shfl_xor(v, o));
    return v;
}

// async global->LDS, 16B per lane. LDS dest is wave-uniform base + lane*16.
__device__ __forceinline__ void gl_lds16(const void* g, void* l) {
    __builtin_amdgcn_global_load_lds(
        (__attribute__((address_space(1))) void*)g,
        (__attribute__((address_space(3))) void*)l, 16, 0, 0);
}

// ---------------------------------------------------------------------------
// Big-GEMM (Kproj / VT): C = A(M,512) @ Bt(N,512)^T [+bias][*affc], bf16 out.
// BM=256, BN=128, BK=64, K=512 fixed (8 K-tiles). 512 threads = 8 waves
// (4M x 2N), per-wave C = 64x64 (4x4 16x16 frags). LDS: 3 buffers
// (A 32KB + B 16KB each) = 144KB -> 1 block/CU.
// Pipeline: during tile t, prefetch tile t+2 into buf[(t+2)%3] (free since
// t-1); end of tile t waits vmcnt(6) = drains t+1's 6 loads, leaves t+2's
// 6 in flight. Raw s_barrier; no vmcnt(0) until the tail.
// ---------------------------------------------------------------------------
template<bool BIAS_ROW, bool AFFC>
__global__ __launch_bounds__(512, 1) void gemm256_bt_k(
    const u16* __restrict__ A, const u16* __restrict__ Bt,
    const float* __restrict__ bias, u16* __restrict__ Cout,
    int lda, int ldb, int ldc, long sA2, long sB2, long sC2,
    const float* __restrict__ affc)
{
    __shared__ u16 As[3][256][64];   // 98304 B
    __shared__ u16 Bs[3][128][64];   // 49152 B
    const int t = threadIdx.x;
    const int lane = t & 63;
    const int wave = t >> 6;          // 0..7
    const int z = blockIdx.z;
    A  += (long)z * sA2;
    Bt += (long)z * sB2;
    const long cbase = (long)z * sC2;
    const int n0 = blockIdx.x * 128;
    const int m0 = blockIdx.y * 256;
    const int wm = wave >> 1;         // 0..3  (64-row slab)
    const int wn = wave & 1;          // 0..1  (64-col slab)
    const int rl = lane & 15, uq = lane >> 4;
    const int srow = lane >> 3;       // 0..7
    const int up   = lane & 7;        // 16B unit

    f32x4 acc[4][4];
#pragma unroll
    for (int i = 0; i < 4; ++i)
#pragma unroll
        for (int j = 0; j < 4; ++j) acc[i][j] = (f32x4){0.f, 0.f, 0.f, 0.f};

    // one stage = 6 global_load_lds per wave (A: 4 rounds, B: 2 rounds)
    auto stage = [&](int buf, int kt) {
        const int k0 = kt * 64;
#pragma unroll
        for (int r = 0; r < 4; ++r) {
            const int row = r * 64 + wave * 8 + srow;
            const int ul = up ^ (row & 7);
            gl_lds16(A + (long)(m0 + row) * lda + k0 + ul * 8,
                     &As[buf][r * 64 + wave * 8][0]);
        }
#pragma unroll
        for (int r = 0; r < 2; ++r) {
            const int row = r * 64 + wave * 8 + srow;
            const int ul = up ^ (row & 7);
            gl_lds16(Bt + (long)(n0 + row) * ldb + k0 + ul * 8,
                     &Bs[buf][r * 64 + wave * 8][0]);
        }
    };

    auto compute = [&](int buf) {
        short8 af[2][4], bf[2][4];
#pragma unroll
        for (int kc = 0; kc < 2; ++kc) {
#pragma unroll
            for (int i = 0; i < 4; ++i) {
                const int R = wm * 64 + i * 16 + rl;
                af[kc][i] = *(const short8*)(&As[buf][R][((kc * 4 + uq) ^ (R & 7)) * 8]);
            }
#pragma unroll
            for (int j = 0; j < 4; ++j) {
                const int R = wn * 64 + j * 16 + rl;
                bf[kc][j] = *(const short8*)(&Bs[buf][R][((kc * 4 + uq) ^ (R & 7)) * 8]);
            }
        }
        __builtin_amdgcn_s_setprio(1);
#pragma unroll
        for (int kc = 0; kc < 2; ++kc)
#pragma unroll
            for (int i = 0; i < 4; ++i)
#pragma unroll
                for (int j = 0; j < 4; ++j)
                    acc[i][j] = __builtin_amdgcn_mfma_f32_16x16x32_bf16(
                        af[kc][i], bf[kc][j], acc[i][j], 0, 0, 0);
        __builtin_amdgcn_s_setprio(0);
    };

    // prologue: stage tiles 0,1; drain tile0 (oldest 6), keep tile1 in flight
    stage(0, 0);
    stage(1, 1);
    asm volatile("s_waitcnt vmcnt(6)\n\ts_barrier" ::: "memory");

#pragma unroll
    for (int kt = 0; kt < 8; ++kt) {
        if (kt + 2 < 8) stage((kt + 2) % 3, kt + 2);   // buf free since kt-1
        compute(kt % 3);
        if (kt < 6) {
            // drain tile kt+1's 6 loads; tile kt+2's 6 stay outstanding
            asm volatile("s_waitcnt vmcnt(6)\n\ts_barrier" ::: "memory");
        } else if (kt == 6) {
            asm volatile("s_waitcnt vmcnt(0)\n\ts_barrier" ::: "memory");
        }
    }

    const int r0 = (lane >> 4) * 4;
    const int c0 = lane & 15;
#pragma unroll
    for (int i = 0; i < 4; ++i) {
#pragma unroll
        for (int j = 0; j < 4; ++j) {
#pragma unroll
            for (int r = 0; r < 4; ++r) {
                const int row = m0 + wm * 64 + i * 16 + r0 + r;
                const int col = n0 + wn * 64 + j * 16 + c0;
                float v = acc[i][j][r];
                if constexpr (BIAS_ROW) v += bias[row]; else v += bias[col];
                if constexpr (AFFC) v *= affc[(long)z * 4096 + col];
                Cout[cbase + (long)row * ldc + col] = f2b(v);
            }
        }
    }
}

// ---------------------------------------------------------------------------
// Generic batched GEMM (R3 form):  C = alpha*A(M,K)@Bt(N,K)^T [+bias][*affc]
// BK=64 rows of 128B (8 x 16B units), unit swizzle u^(row&7), single-buffered.
// ---------------------------------------------------------------------------
template<int TM, int TN, bool OUT_BF16, bool RELU, bool BIAS_ROW, bool HAS_BIAS,
         bool AFFC, bool SMAX>
__global__ __launch_bounds__(256) void gemm_bt_k(
    const u16* __restrict__ A, const u16* __restrict__ Bt,
    const float* __restrict__ bias, void* __restrict__ Cout,
    int K, int lda, int ldb, int ldc,
    int bdiv, long sA1, long sA2, long sB1, long sB2, long sC1, long sC2,
    float alpha, const float* __restrict__ affc, const float2* __restrict__ stats)
{
    __shared__ u16 As[TM][64];
    __shared__ u16 Bs[TN][64];
    const int t = threadIdx.x;
    const int lane = t & 63;
    const int wave = t >> 6;
    const int z = blockIdx.z;
    const int zq = z / bdiv, zr = z % bdiv;
    A  += (long)zq * sA1 + (long)zr * sA2;
    Bt += (long)zq * sB1 + (long)zr * sB2;
    const long cbase = (long)zq * sC1 + (long)zr * sC2;
    const int n0 = blockIdx.x * TN;
    const int m0 = blockIdx.y * TM;
    constexpr int FM = TM / 32, FN = TN / 32;
    const int wr = wave >> 1, wc = wave & 1;
    const int rl = lane & 15, uq = lane >> 4;

    float2 st[FM];
    if constexpr (SMAX) {
#pragma unroll
        for (int i = 0; i < FM; ++i)
            st[i] = stats[zr * 64 + m0 + wr * (TM / 2) + i * 16 + rl];
    }

    f32x4 acc[FM][FN];
#pragma unroll
    for (int i = 0; i < FM; ++i)
#pragma unroll
        for (int j = 0; j < FN; ++j) acc[i][j] = (f32x4){0.f, 0.f, 0.f, 0.f};

    const int srow = lane >> 3;
    const int up   = lane & 7;

    for (int k0 = 0; k0 < K; k0 += 64) {
        __syncthreads();
#pragma unroll
        for (int r = 0; r < TM / 32; ++r) {
            const int br = (wave * (TM / 32) + r) * 8;
            const int row = br + srow;
            const int ul = up ^ (row & 7);
            gl_lds16(A + (long)(m0 + row) * lda + k0 + ul * 8, &As[br][0]);
        }
#pragma unroll
        for (int r = 0; r < TN / 32; ++r) {
            const int br = (wave * (TN / 32) + r) * 8;
            const int row = br + srow;
            const int ul = up ^ (row & 7);
            gl_lds16(Bt + (long)(n0 + row) * ldb + k0 + ul * 8, &Bs[br][0]);
        }
        __syncthreads();   // drains vmcnt (global_load_lds)

#pragma unroll
        for (int kc = 0; kc < 2; ++kc) {
            short8 af[FM], bf[FN];
#pragma unroll
            for (int i = 0; i < FM; ++i) {
                const int R = wr * (TM / 2) + i * 16 + rl;
                af[i] = *(const short8*)(&As[R][((kc * 4 + uq) ^ (R & 7)) * 8]);
                if constexpr (SMAX) {
#pragma unroll
                    for (int e = 0; e < 8; ++e)
                        af[i][e] = (short)f2b(
                            __expf(b2f((u16)af[i][e]) - st[i].x) * st[i].y);
                }
            }
#pragma unroll
            for (int j = 0; j < FN; ++j) {
                const int R = wc * (TN / 2) + j * 16 + rl;
                bf[j] = *(const short8*)(&Bs[R][((kc * 4 + uq) ^ (R & 7)) * 8]);
            }
#pragma unroll
            for (int i = 0; i < FM; ++i)
#pragma unroll
                for (int j = 0; j < FN; ++j)
                    acc[i][j] = __builtin_amdgcn_mfma_f32_16x16x32_bf16(
                        af[i], bf[j], acc[i][j], 0, 0, 0);
        }
    }

    const int r0 = (lane >> 4) * 4;
    const int c0 = lane & 15;
#pragma unroll
    for (int i = 0; i < FM; ++i) {
#pragma unroll
        for (int j = 0; j < FN; ++j) {
#pragma unroll
            for (int r = 0; r < 4; ++r) {
                const int row = m0 + wr * (TM / 2) + i * 16 + r0 + r;
                const int col = n0 + wc * (TN / 2) + j * 16 + c0;
                float v = acc[i][j][r] * alpha;
                if constexpr (HAS_BIAS) {
                    if constexpr (BIAS_ROW) v += bias[row]; else v += bias[col];
                }
                if constexpr (AFFC) v *= affc[(long)zq * 4096 + col];
                if constexpr (RELU) v = fmaxf(v, 0.f);
                const long idx = cbase + (long)row * ldc + col;
                if constexpr (OUT_BF16) ((u16*)Cout)[idx] = f2b(v);
                else                    ((float*)Cout)[idx] = v;
            }
        }
    }
}

// ---------------------------------------------------------------------------
// softmax stats (m, 1/sum) per (b,h,q) + head-averaged score output.
// ---------------------------------------------------------------------------
__global__ __launch_bounds__(256) void smstats_k(
    const u16* __restrict__ S, float2* __restrict__ stats,
    float* __restrict__ attns)
{
    const int bq = blockIdx.x;
    const int b = bq >> 6, q = bq & 63;
    const int t = threadIdx.x;
    const int w = t >> 6, lane = t & 63;
    __shared__ float red[4];
    const int kb = t * 16;

    float attnacc[16];
#pragma unroll
    for (int j = 0; j < 16; ++j) attnacc[j] = 0.f;

    for (int h = 0; h < 8; ++h) {
        const long roff = (((long)(b * 8 + h)) * 64 + q) * 4096;
        const u16* Srow = S + roff;
        float v[16];
        short8 s0 = *(const short8*)(Srow + kb);
        short8 s1 = *(const short8*)(Srow + kb + 8);
#pragma unroll
        for (int j = 0; j < 8; ++j) { v[j] = b2f((u16)s0[j]); v[8 + j] = b2f((u16)s1[j]); }

        float m = -3.0e38f;
#pragma unroll
        for (int j = 0; j < 16; ++j) m = fmaxf(m, v[j]);
        m = waveMax(m);
        __syncthreads();
        if (lane == 0) red[w] = m;
        __syncthreads();
        m = fmaxf(fmaxf(red[0], red[1]), fmaxf(red[2], red[3]));

        float s = 0.f;
#pragma unroll
        for (int j = 0; j < 16; ++j) s += __expf(v[j] - m);
        s = waveSum(s);
        __syncthreads();
        if (lane == 0) red[w] = s;
        __syncthreads();
        s = red[0] + red[1] + red[2] + red[3];

        if (t == 0) stats[(b * 8 + h) * 64 + q] = make_float2(m, 1.f / s);
#pragma unroll
        for (int j = 0; j < 16; ++j) attnacc[j] += v[j];
    }
    float* arow = attns + (long)bq * 4096;
#pragma unroll
    for (int j = 0; j < 16; ++j) arow[kb + j] = attnacc[j] * 0.125f;  // /H
}

// ---------------------------------------------------------------------------
// split-K PV reduce: part (8,128,64,64) fp32 -> o16 (16,64,512) bf16
// ---------------------------------------------------------------------------
__global__ __launch_bounds__(256) void pv_reduce_k(
    const float* __restrict__ part, u16* __restrict__ o16)
{
    const int i = blockIdx.x * 256 + threadIdx.x;
    const int d4 = i & 15;
    const int q  = (i >> 4) & 63;
    const int bh = i >> 10;
    const float* p = part + (long)bh * 4096 + q * 64 + d4 * 4;
    float4 s = {0.f, 0.f, 0.f, 0.f};
#pragma unroll
    for (int sp = 0; sp < 8; ++sp) {
        const float4 v = *(const float4*)(p + (long)sp * 524288);
        s.x += v.x; s.y += v.y; s.z += v.z; s.w += v.w;
    }
    const int b = bh >> 3, h = bh & 7;
    u16* o = o16 + (long)b * 32768 + q * 512 + h * 64 + d4 * 4;
    short4v r;
    r[0] = (short)f2b(s.x); r[1] = (short)f2b(s.y);
    r[2] = (short)f2b(s.z); r[3] = (short)f2b(s.w);
    *(short4v*)o = r;
}

// split-K FF2 reduce + bias
__global__ __launch_bounds__(256) void ffred_k(
    const float* __restrict__ part, const float* __restrict__ bias,
    float* __restrict__ out)
{
    const int i = (blockIdx.x * 256 + threadIdx.x) * 4;
    const int c = i & 511;
    float4 s = *(const float4*)(part + i);
#pragma unroll
    for (int sp = 1; sp < 4; ++sp) {
        const float4 v = *(const float4*)(part + (long)sp * 524288 + i);
        s.x += v.x; s.y += v.y; s.z += v.z; s.w += v.w;
    }
    s.x += bias[c]; s.y += bias[c + 1]; s.z += bias[c + 2]; s.w += bias[c + 3];
    *(float4*)(out + i) = s;
}

// u[l][b][c'] = sum_c Wk[l][c'][c] * extra[b][c]
__global__ __launch_bounds__(256) void umat_k(
    const float* __restrict__ Wk, const float* __restrict__ extra,
    float* __restrict__ u)
{
    __shared__ float ex[16][512];
    const int l = blockIdx.x;
    const int t = threadIdx.x;
    for (int i = t; i < 16 * 512 / 4; i += 256)
        ((float4*)&ex[0][0])[i] = ((const float4*)extra)[i];
    __syncthreads();
    const int lane = t & 63, wave = t >> 6;
    const int row = blockIdx.y * 4 + wave;
    const float* wrow = Wk + ((size_t)l * 512 + row) * 512 + lane * 8;
    float w[8];
#pragma unroll
    for (int j = 0; j < 8; ++j) w[j] = wrow[j];
    float s[16];
#pragma unroll
    for (int b = 0; b < 16; ++b) {
        float x = 0.f;
#pragma unroll
        for (int j = 0; j < 8; ++j) x += w[j] * ex[b][lane * 8 + j];
        s[b] = waveSum(x);
    }
    if (lane < 16) u[((size_t)l * 16 + lane) * 512 + row] = s[lane];
}

// cb[l*16+b] = dot(extra[b], bk[l])
__global__ __launch_bounds__(256) void cbk_k(
    const float* __restrict__ bk, const float* __restrict__ extra,
    float* __restrict__ cb)
{
    const int gw = blockIdx.x * 4 + (threadIdx.x >> 6);
    const int lane = threadIdx.x & 63;
    const int l = gw >> 4, b = gw & 15;
    float s = 0.f;
#pragma unroll
    for (int j = 0; j < 8; ++j)
        s += extra[b * 512 + lane * 8 + j] * bk[l * 512 + lane * 8 + j];
    s = waveSum(s);
    if (lane == 0) cb[gw] = s;
}

// feat fp32 -> bf16, fused with aff for all 3 layers
__global__ __launch_bounds__(256) void cvt16_aff_k(
    const float* __restrict__ feat, u16* __restrict__ dst,
    const float* __restrict__ u, const float* __restrict__ cb,
    float* __restrict__ affb, float* __restrict__ affs_out)
{
    const int t = blockIdx.x * 256 + threadIdx.x;
    const long i = (long)t * 8;
    const int lane = threadIdx.x & 63;
    const int r = t >> 6;
    const int b = r >> 12;
    const float4 a0 = *(const float4*)(feat + i);
    const float4 a1 = *(const float4*)(feat + i + 4);
    short8 o;
    o[0] = (short)f2b(a0.x); o[1] = (short)f2b(a0.y);
    o[2] = (short)f2b(a0.z); o[3] = (short)f2b(a0.w);
    o[4] = (short)f2b(a1.x); o[5] = (short)f2b(a1.y);
    o[6] = (short)f2b(a1.z); o[7] = (short)f2b(a1.w);
    *(short8*)(dst + i) = o;
    const float f[8] = {a0.x, a0.y, a0.z, a0.w, a1.x, a1.y, a1.z, a1.w};
#pragma unroll
    for (int l = 0; l < 3; ++l) {
        const float* ur = u + ((size_t)l * 16 + b) * 512 + lane * 8;
        float s = 0.f;
#pragma unroll
        for (int j = 0; j < 8; ++j) s += f[j] * ur[j];
        s = waveSum(s);
        if (lane == 0) {
            const float av = 1.f / (1.f + __expf(-0.015625f * (s + cb[l * 16 + b])));
            affb[l * 65536 + r] = av;
            affs_out[l * 65536 + r] = av;
        }
    }
}

// x = LN(x + add; g, beta)
template<bool WRITE_OUT>
__global__ __launch_bounds__(256) void ln_k(
    float* __restrict__ x, const float* __restrict__ add,
    const float* __restrict__ g, const float* __restrict__ be,
    u16* __restrict__ x16, float* __restrict__ outp)
{
    const int r = blockIdx.x, t = threadIdx.x;
    const int w = t >> 6, lane = t & 63;
    __shared__ float red[4];
    float* xr = x + (long)r * 512;
    const float* ar = add + (long)r * 512;
    const float v0 = xr[2 * t]     + ar[2 * t];
    const float v1 = xr[2 * t + 1] + ar[2 * t + 1];
    float s = waveSum(v0 + v1);
    if (lane == 0) red[w] = s;
    __syncthreads();
    s = red[0] + red[1] + red[2] + red[3];
    const float mu = s * (1.f / 512.f);
    const float d0 = v0 - mu, d1 = v1 - mu;
    __syncthreads();
    float vs = waveSum(d0 * d0 + d1 * d1);
    if (lane == 0) red[w] = vs;
    __syncthreads();
    vs = red[0] + red[1] + red[2] + red[3];
    const float rs = rsqrtf(vs * (1.f / 512.f) + 1e-5f);
    const float o0 = g[2 * t]     * d0 * rs + be[2 * t];
    const float o1 = g[2 * t + 1] * d1 * rs + be[2 * t + 1];
    xr[2 * t] = o0; xr[2 * t + 1] = o1;
    x16[(long)r * 512 + 2 * t]     = f2b(o0);
    x16[(long)r * 512 + 2 * t + 1] = f2b(o1);
    if constexpr (WRITE_OUT) {
        outp[(long)r * 512 + 2 * t]     = o0;
        outp[(long)r * 512 + 2 * t + 1] = o1;
    }
}

// x = copy(queries) fp32 + bf16
__global__ __launch_bounds__(256) void initx_k(
    const float* __restrict__ src, float* __restrict__ x, u16* __restrict__ x16)
{
    const long i = ((long)blockIdx.x * 256 + threadIdx.x) * 8;
    const float4 a = *(const float4*)(src + i);
    const float4 b = *(const float4*)(src + i + 4);
    *(float4*)(x + i) = a;
    *(float4*)(x + i + 4) = b;
    short8 r;
    r[0] = (short)f2b(a.x); r[1] = (short)f2b(a.y); r[2] = (short)f2b(a.z); r[3] = (short)f2b(a.w);
    r[4] = (short)f2b(b.x); r[5] = (short)f2b(b.y); r[6] = (short)f2b(b.z); r[7] = (short)f2b(b.w);
    *(short8*)(x16 + i) = r;
}

// W (K,N) fp32 -> WT (N,K) bf16, batched over blockIdx.z
__global__ __launch_bounds__(256) void transpose_w_k(
    const float* __restrict__ W, u16* __restrict__ WT, int K, int N)
{
    __shared__ float tile[32][33];
    const int z = blockIdx.z;
    W  += (size_t)z * K * N;
    WT += (size_t)z * K * N;
    const int n0 = blockIdx.x * 32, k0 = blockIdx.y * 32;
    const int tx = threadIdx.x & 31, ty = threadIdx.x >> 5;
#pragma unroll
    for (int j = 0; j < 32; j += 8)
        tile[ty + j][tx] = W[(size_t)(k0 + ty + j) * N + n0 + tx];
    __syncthreads();
#pragma unroll
    for (int j = 0; j < 32; j += 8)
        WT[(size_t)(n0 + ty + j) * K + k0 + tx] = f2b(tile[tx][ty + j]);
}

// ---------------------------------------------------------------------------
extern "C" void kernel_launch(void* const* d_in, const int* in_sizes, int n_in,
                              void* d_out, int out_size, void* d_ws, size_t ws_size,
                              hipStream_t stream)
{
    (void)in_sizes; (void)n_in; (void)out_size; (void)ws_size;
    const float* queries = (const float*)d_in[0];
    const float* feat    = (const float*)d_in[1];
    const float* extra   = (const float*)d_in[2];
    const float* Wq = (const float*)d_in[3];  const float* bq = (const float*)d_in[4];
    const float* Wk = (const float*)d_in[5];  const float* bk = (const float*)d_in[6];
    const float* Wv = (const float*)d_in[7];  const float* bv = (const float*)d_in[8];
    const float* Wo = (const float*)d_in[9];  const float* bo = (const float*)d_in[10];
    const float* W1 = (const float*)d_in[11]; const float* b1 = (const float*)d_in[12];
    const float* W2 = (const float*)d_in[13]; const float* b2 = (const float*)d_in[14];
    const float* g2 = (const float*)d_in[15]; const float* be2 = (const float*)d_in[16];
    const float* g3 = (const float*)d_in[17]; const float* be3 = (const float*)d_in[18];

    char* wsb = (char*)d_ws;
    size_t off = 0;
    auto alloc = [&](size_t bytes) -> char* {
        char* p = wsb + off; off += (bytes + 255) & ~(size_t)255; return p;
    };
    u16*  feat16 = (u16*)alloc(33554432ull * 2);   // (B*Nk, C) bf16
    u16*  WqT = (u16*)alloc(786432ull * 2);        // (L,512,512) transposed
    u16*  WkT = (u16*)alloc(786432ull * 2);
    u16*  WvT = (u16*)alloc(786432ull * 2);
    u16*  WoT = (u16*)alloc(786432ull * 2);
    u16*  W1T = (u16*)alloc(3145728ull * 2);       // (L,2048,512)
    u16*  W2T = (u16*)alloc(3145728ull * 2);       // (L,512,2048)
    u16*  K16 = (u16*)alloc(33554432ull * 2);      // (B,Nk,C); later PV partials
    u16*  VT16 = (u16*)alloc(33554432ull * 2);     // (B,C,Nk) aff-gated; later FF2 partials
    u16*  q16 = (u16*)alloc(524288ull * 2);        // (B*Nq, C)
    u16*  S16 = (u16*)alloc(33554432ull * 2);      // (B,H,64,4096) scores*SCALE
    float* affb  = (float*)alloc(196608ull * 4);   // (L,B,Nk)
    u16*  o16 = (u16*)alloc(524288ull * 2);        // attention out (B,Nq,C)
    float* oproj = (float*)alloc(524288ull * 4);
    float* xb    = (float*)alloc(524288ull * 4);
    u16*  x16 = (u16*)alloc(524288ull * 2);
    u16*  h116 = (u16*)alloc(2097152ull * 2);      // (B*Nq, 2048)
    float* ffb   = (float*)alloc(524288ull * 4);
    float* uvec  = (float*)alloc(24576ull * 4);    // (L,16,512)
    float* cb    = (float*)alloc(48ull * 4);
    float2* stats = (float2*)alloc(8192ull * 8);   // (B*H*64) {m, 1/sum}
    float* partPV = (float*)K16;                   // alias: K dead after S-GEMM
    float* part2  = (float*)VT16;                  // alias: VT dead after PV

    float* out_f = (float*)d_out;
    float* outs_base  = out_f;                     // (3,16,64,512)
    float* attns_base = out_f + 1572864;           // (3,16,64,4096)
    float* affs_base  = out_f + 14155776;          // (3,16,1,1,4096)

    // prep (layer-independent)
    umat_k<<<dim3(3, 128), 256, 0, stream>>>(Wk, extra, uvec);
    cbk_k<<<12, 256, 0, stream>>>(bk, extra, cb);
    cvt16_aff_k<<<16384, 256, 0, stream>>>(feat, feat16, uvec, cb, affb, affs_base);
    initx_k<<<256, 256, 0, stream>>>(queries, xb, x16);
    transpose_w_k<<<dim3(16, 16, 3), 256, 0, stream>>>(Wq, WqT, 512, 512);
    transpose_w_k<<<dim3(16, 16, 3), 256, 0, stream>>>(Wk, WkT, 512, 512);
    transpose_w_k<<<dim3(16, 16, 3), 256, 0, stream>>>(Wv, WvT, 512, 512);
    transpose_w_k<<<dim3(16, 16, 3), 256, 0, stream>>>(Wo, WoT, 512, 512);
    transpose_w_k<<<dim3(64, 16, 3), 256, 0, stream>>>(W1, W1T, 512, 2048);
    transpose_w_k<<<dim3(16, 64, 3), 256, 0, stream>>>(W2, W2T, 2048, 512);

    for (int i = 0; i < 3; ++i) {
        // K = feat @ Wk + bk   (M=65536, N=512, K=512) -> bf16 (B,Nk,C)
        gemm256_bt_k<false, false><<<dim3(4, 256, 1), 512, 0, stream>>>(
            feat16, WkT + i * 262144, bk + i * 512, K16,
            512, 512, 512, 0, 0, 0, nullptr);
        // VT'[b] = aff ⊙ ((feat[b] @ Wv)^T + bv)  -> (B,C,Nk)
        gemm256_bt_k<true, true><<<dim3(32, 2, 16), 512, 0, stream>>>(
            WvT + i * 262144, feat16, bv + i * 512, VT16,
            512, 512, 4096, 0, 2097152, 2097152, affb + i * 65536);
        // q = x @ Wq + bq  (1024 x 512)
        gemm_bt_k<64, 64, true, false, false, true, false, false>
            <<<dim3(8, 16, 1), 256, 0, stream>>>(
            x16, WqT + i * 262144, bq + i * 512, q16,
            512, 512, 512, 512, 1, 0, 0, 0, 0, 0, 0, 1.f, nullptr, nullptr);
        // S[b,h] = SCALE * q_h @ K_h^T   (batch 128: M=64,N=4096,K=64)
        gemm_bt_k<64, 128, true, false, false, false, false, false>
            <<<dim3(32, 1, 128), 256, 0, stream>>>(
            q16, K16, nullptr, S16,
            64, 512, 512, 4096, 8, 32768, 64, 2097152, 64, 2097152, 262144,
            0.125f, nullptr, nullptr);
        // softmax stats + attns
        smstats_k<<<1024, 256, 0, stream>>>(
            S16, stats, attns_base + (size_t)i * 4194304);
        // o[b,h] = softmax(S) @ V', split-K 8, softmax fused at fragment load
        gemm_bt_k<64, 64, false, false, false, false, false, true>
            <<<dim3(1, 1, 1024), 256, 0, stream>>>(
            S16, VT16, nullptr, partPV,
            512, 4096, 4096, 64, 128, 512, 262144, 512, 262144, 524288, 4096,
            1.f, nullptr, stats);
        pv_reduce_k<<<512, 256, 0, stream>>>(partPV, o16);
        // o @ Wo + bo -> fp32
        gemm_bt_k<64, 64, false, false, false, true, false, false>
            <<<dim3(8, 16, 1), 256, 0, stream>>>(
            o16, WoT + i * 262144, bo + i * 512, oproj,
            512, 512, 512, 512, 1, 0, 0, 0, 0, 0, 0, 1.f, nullptr, nullptr);
        // x = LN(x + oproj; g2, beta2)
        ln_k<false><<<1024, 256, 0, stream>>>(xb, oproj, g2 + i * 512, be2 + i * 512, x16, nullptr);
        // h1 = relu(x @ W1 + b1) -> bf16 (1024 x 2048)
        gemm_bt_k<64, 128, true, true, false, true, false, false>
            <<<dim3(16, 16, 1), 256, 0, stream>>>(
            x16, W1T + (size_t)i * 1048576, b1 + i * 2048, h116,
            512, 512, 512, 2048, 1, 0, 0, 0, 0, 0, 0, 1.f, nullptr, nullptr);
        // ff partials = h1 @ W2 (split-K 4) -> fp32 (4,1024,512)
        gemm_bt_k<64, 64, false, false, false, false, false, false>
            <<<dim3(8, 16, 4), 256, 0, stream>>>(
            h116, W2T + (size_t)i * 1048576, nullptr, part2,
            512, 2048, 2048, 512, 1, 512, 0, 512, 0, 524288, 0,
            1.f, nullptr, nullptr);
        ffred_k<<<512, 256, 0, stream>>>(part2, b2 + i * 512, ffb);
        // x = LN(x + ff; g3, beta3), write outs[i]
        ln_k<true><<<1024, 256, 0, stream>>>(xb, ffb, g3 + i * 512, be3 + i * 512, x16,
                                             outs_base + (size_t)i * 524288);
    }
}

// Round 8
// 777.259 us; speedup vs baseline: 1.4349x; 1.0509x over previous
//
#include <hip/hip_runtime.h>

// SegDecoder: 3-layer cross-attention decoder on MI355X (gfx950).
// B=16, Nq=64, Nk=4096, C=512, H=8, hd=64, FF=2048, L=3.
// R8: Kproj/VT on a 256x256-tile BK=64 8-wave GEMM (staged volume 384->256MB,
// the one knob all prior null experiments held constant), 2-buf stage-first
// single-barrier loop (R6-proven safe), XCD-chunk swizzle (R4-proven FETCH cut).

typedef unsigned short u16;
typedef __attribute__((ext_vector_type(8))) short short8;
typedef __attribute__((ext_vector_type(4))) short short4v;
typedef __attribute__((ext_vector_type(4))) float f32x4;

__device__ __forceinline__ float b2f(u16 u) {
    union { unsigned int i; float f; } v; v.i = ((unsigned int)u) << 16; return v.f;
}
__device__ __forceinline__ u16 f2b(float f) {  // round-to-nearest-even
    unsigned int x = __float_as_uint(f);
    x += 0x7fffu + ((x >> 16) & 1u);
    return (u16)(x >> 16);
}

__device__ __forceinline__ float waveSum(float v) {
#pragma unroll
    for (int o = 32; o > 0; o >>= 1) v += __shfl_xor(v, o);
    return v;
}
__device__ __forceinline__ float waveMax(float v) {
#pragma unroll
    for (int o = 32; o > 0; o >>= 1) v = fmaxf(v, __shfl_xor(v, o));
    return v;
}

// async global->LDS, 16B per lane. LDS dest is wave-uniform base + lane*16.
__device__ __forceinline__ void gl_lds16(const void* g, void* l) {
    __builtin_amdgcn_global_load_lds(
        (__attribute__((address_space(1))) void*)g,
        (__attribute__((address_space(3))) void*)l, 16, 0, 0);
}

// ---------------------------------------------------------------------------
// Big-GEMM (Kproj / VT): C = A(M,512) @ Bt(N,512)^T [+bias][*affc], bf16 out.
// BM=BN=256, BK=64, K=512 fixed. 512 threads = 8 waves (2M x 4N), per-wave
// C = 128x64 (8x4 16x16 frags, 128 VGPR acc). LDS 2 x (A 32KB + B 32KB) =
// 128KB -> 1 block/CU. Loop: stage(next, buf^1) BEFORE compute(cur, buf);
// one __syncthreads per K-tile. XCD-chunk block swizzle (bijective).
// Staged volume = (M N)/(BM BN) * (BM+BN) KB/64rows: 256MB vs 384MB at BN=128.
// ---------------------------------------------------------------------------
template<bool BIAS_ROW, bool HAS_BIAS, bool AFFC>
__global__ __launch_bounds__(512, 1) void gemm256x256_k(
    const u16* __restrict__ A, const u16* __restrict__ Bt,
    const float* __restrict__ bias, u16* __restrict__ Cout,
    int lda, int ldb, int ldc, long sA2, long sB2, long sC2,
    const float* __restrict__ affc)
{
    __shared__ u16 As[2][256][64];   // 65536 B
    __shared__ u16 Bs[2][256][64];   // 65536 B
    const int t = threadIdx.x;
    const int lane = t & 63;
    const int wave = t >> 6;          // 0..7

    // bijective XCD-chunk swizzle (m204)
    const int gx = gridDim.x, gy = gridDim.y;
    const int nwg = gx * gy * gridDim.z;
    int id;
    {
        const int orig = blockIdx.x + blockIdx.y * gx + blockIdx.z * gx * gy;
        const int qq = nwg >> 3, rr = nwg & 7;
        const int xcd = orig & 7, sub = orig >> 3;
        id = (xcd < rr ? xcd * (qq + 1) : rr * (qq + 1) + (xcd - rr) * qq) + sub;
    }
    const int bx = id % gx;
    const int by = (id / gx) % gy;
    const int z  = id / (gx * gy);

    A  += (long)z * sA2;
    Bt += (long)z * sB2;
    const long cbase = (long)z * sC2;
    const int n0 = bx * 256;
    const int m0 = by * 256;
    const int wm = wave >> 2;         // 0..1  (128-row slab)
    const int wn = wave & 3;          // 0..3  (64-col slab)
    const int rl = lane & 15, uq = lane >> 4;
    const int srow = lane >> 3;       // 0..7
    const int up   = lane & 7;        // 16B unit

    f32x4 acc[8][4];
#pragma unroll
    for (int i = 0; i < 8; ++i)
#pragma unroll
        for (int j = 0; j < 4; ++j) acc[i][j] = (f32x4){0.f, 0.f, 0.f, 0.f};

    // one stage = 8 gl_lds per wave (A: 4 rounds of 64 rows, B: 4 rounds)
    auto stage = [&](int buf, int kt) {
        const int k0 = kt * 64;
#pragma unroll
        for (int r = 0; r < 4; ++r) {
            const int row = r * 64 + wave * 8 + srow;
            const int ul = up ^ (row & 7);
            gl_lds16(A + (long)(m0 + row) * lda + k0 + ul * 8,
                     &As[buf][r * 64 + wave * 8][0]);
        }
#pragma unroll
        for (int r = 0; r < 4; ++r) {
            const int row = r * 64 + wave * 8 + srow;
            const int ul = up ^ (row & 7);
            gl_lds16(Bt + (long)(n0 + row) * ldb + k0 + ul * 8,
                     &Bs[buf][r * 64 + wave * 8][0]);
        }
    };

    auto compute = [&](int buf) {
#pragma unroll
        for (int kc = 0; kc < 2; ++kc) {
            short8 af[8], bf[4];
#pragma unroll
            for (int i = 0; i < 8; ++i) {
                const int R = wm * 128 + i * 16 + rl;
                af[i] = *(const short8*)(&As[buf][R][((kc * 4 + uq) ^ (R & 7)) * 8]);
            }
#pragma unroll
            for (int j = 0; j < 4; ++j) {
                const int R = wn * 64 + j * 16 + rl;
                bf[j] = *(const short8*)(&Bs[buf][R][((kc * 4 + uq) ^ (R & 7)) * 8]);
            }
            __builtin_amdgcn_s_setprio(1);
#pragma unroll
            for (int i = 0; i < 8; ++i)
#pragma unroll
                for (int j = 0; j < 4; ++j)
                    acc[i][j] = __builtin_amdgcn_mfma_f32_16x16x32_bf16(
                        af[i], bf[j], acc[i][j], 0, 0, 0);
            __builtin_amdgcn_s_setprio(0);
        }
    };

    stage(0, 0);
    __syncthreads();
    int buf = 0;
#pragma unroll
    for (int kt = 0; kt < 8; ++kt) {
        if (kt + 1 < 8) stage(buf ^ 1, kt + 1);   // issue BEFORE compute
        compute(buf);
        __syncthreads();                           // drain stage(kt+1); barrier
        buf ^= 1;
    }

    const int r0 = (lane >> 4) * 4;
    const int c0 = lane & 15;
#pragma unroll
    for (int i = 0; i < 8; ++i) {
#pragma unroll
        for (int j = 0; j < 4; ++j) {
#pragma unroll
            for (int r = 0; r < 4; ++r) {
                const int row = m0 + wm * 128 + i * 16 + r0 + r;
                const int col = n0 + wn * 64 + j * 16 + c0;
                float v = acc[i][j][r];
                if constexpr (HAS_BIAS) {
                    if constexpr (BIAS_ROW) v += bias[row]; else v += bias[col];
                }
                if constexpr (AFFC) v *= affc[(long)z * 4096 + col];
                Cout[cbase + (long)row * ldc + col] = f2b(v);
            }
        }
    }
}

// ---------------------------------------------------------------------------
// Generic batched GEMM (R3 form):  C = alpha*A(M,K)@Bt(N,K)^T [+bias][*affc]
// BK=64 rows of 128B (8 x 16B units), unit swizzle u^(row&7), single-buffered.
// ---------------------------------------------------------------------------
template<int TM, int TN, bool OUT_BF16, bool RELU, bool BIAS_ROW, bool HAS_BIAS,
         bool AFFC, bool SMAX>
__global__ __launch_bounds__(256) void gemm_bt_k(
    const u16* __restrict__ A, const u16* __restrict__ Bt,
    const float* __restrict__ bias, void* __restrict__ Cout,
    int K, int lda, int ldb, int ldc,
    int bdiv, long sA1, long sA2, long sB1, long sB2, long sC1, long sC2,
    float alpha, const float* __restrict__ affc, const float2* __restrict__ stats)
{
    __shared__ u16 As[TM][64];
    __shared__ u16 Bs[TN][64];
    const int t = threadIdx.x;
    const int lane = t & 63;
    const int wave = t >> 6;
    const int z = blockIdx.z;
    const int zq = z / bdiv, zr = z % bdiv;
    A  += (long)zq * sA1 + (long)zr * sA2;
    Bt += (long)zq * sB1 + (long)zr * sB2;
    const long cbase = (long)zq * sC1 + (long)zr * sC2;
    const int n0 = blockIdx.x * TN;
    const int m0 = blockIdx.y * TM;
    constexpr int FM = TM / 32, FN = TN / 32;
    const int wr = wave >> 1, wc = wave & 1;
    const int rl = lane & 15, uq = lane >> 4;

    float2 st[FM];
    if constexpr (SMAX) {
#pragma unroll
        for (int i = 0; i < FM; ++i)
            st[i] = stats[zr * 64 + m0 + wr * (TM / 2) + i * 16 + rl];
    }

    f32x4 acc[FM][FN];
#pragma unroll
    for (int i = 0; i < FM; ++i)
#pragma unroll
        for (int j = 0; j < FN; ++j) acc[i][j] = (f32x4){0.f, 0.f, 0.f, 0.f};

    const int srow = lane >> 3;
    const int up   = lane & 7;

    for (int k0 = 0; k0 < K; k0 += 64) {
        __syncthreads();
#pragma unroll
        for (int r = 0; r < TM / 32; ++r) {
            const int br = (wave * (TM / 32) + r) * 8;
            const int row = br + srow;
            const int ul = up ^ (row & 7);
            gl_lds16(A + (long)(m0 + row) * lda + k0 + ul * 8, &As[br][0]);
        }
#pragma unroll
        for (int r = 0; r < TN / 32; ++r) {
            const int br = (wave * (TN / 32) + r) * 8;
            const int row = br + srow;
            const int ul = up ^ (row & 7);
            gl_lds16(Bt + (long)(n0 + row) * ldb + k0 + ul * 8, &Bs[br][0]);
        }
        __syncthreads();   // drains vmcnt (global_load_lds)

#pragma unroll
        for (int kc = 0; kc < 2; ++kc) {
            short8 af[FM], bf[FN];
#pragma unroll
            for (int i = 0; i < FM; ++i) {
                const int R = wr * (TM / 2) + i * 16 + rl;
                af[i] = *(const short8*)(&As[R][((kc * 4 + uq) ^ (R & 7)) * 8]);
                if constexpr (SMAX) {
#pragma unroll
                    for (int e = 0; e < 8; ++e)
                        af[i][e] = (short)f2b(
                            __expf(b2f((u16)af[i][e]) - st[i].x) * st[i].y);
                }
            }
#pragma unroll
            for (int j = 0; j < FN; ++j) {
                const int R = wc * (TN / 2) + j * 16 + rl;
                bf[j] = *(const short8*)(&Bs[R][((kc * 4 + uq) ^ (R & 7)) * 8]);
            }
#pragma unroll
            for (int i = 0; i < FM; ++i)
#pragma unroll
                for (int j = 0; j < FN; ++j)
                    acc[i][j] = __builtin_amdgcn_mfma_f32_16x16x32_bf16(
                        af[i], bf[j], acc[i][j], 0, 0, 0);
        }
    }

    const int r0 = (lane >> 4) * 4;
    const int c0 = lane & 15;
#pragma unroll
    for (int i = 0; i < FM; ++i) {
#pragma unroll
        for (int j = 0; j < FN; ++j) {
#pragma unroll
            for (int r = 0; r < 4; ++r) {
                const int row = m0 + wr * (TM / 2) + i * 16 + r0 + r;
                const int col = n0 + wc * (TN / 2) + j * 16 + c0;
                float v = acc[i][j][r] * alpha;
                if constexpr (HAS_BIAS) {
                    if constexpr (BIAS_ROW) v += bias[row]; else v += bias[col];
                }
                if constexpr (AFFC) v *= affc[(long)zq * 4096 + col];
                if constexpr (RELU) v = fmaxf(v, 0.f);
                const long idx = cbase + (long)row * ldc + col;
                if constexpr (OUT_BF16) ((u16*)Cout)[idx] = f2b(v);
                else                    ((float*)Cout)[idx] = v;
            }
        }
    }
}

// ---------------------------------------------------------------------------
// softmax stats (m, 1/sum) per (b,h,q) + head-averaged score output.
// ---------------------------------------------------------------------------
__global__ __launch_bounds__(256) void smstats_k(
    const u16* __restrict__ S, float2* __restrict__ stats,
    float* __restrict__ attns)
{
    const int bq = blockIdx.x;
    const int b = bq >> 6, q = bq & 63;
    const int t = threadIdx.x;
    const int w = t >> 6, lane = t & 63;
    __shared__ float red[4];
    const int kb = t * 16;

    float attnacc[16];
#pragma unroll
    for (int j = 0; j < 16; ++j) attnacc[j] = 0.f;

    for (int h = 0; h < 8; ++h) {
        const long roff = (((long)(b * 8 + h)) * 64 + q) * 4096;
        const u16* Srow = S + roff;
        float v[16];
        short8 s0 = *(const short8*)(Srow + kb);
        short8 s1 = *(const short8*)(Srow + kb + 8);
#pragma unroll
        for (int j = 0; j < 8; ++j) { v[j] = b2f((u16)s0[j]); v[8 + j] = b2f((u16)s1[j]); }

        float m = -3.0e38f;
#pragma unroll
        for (int j = 0; j < 16; ++j) m = fmaxf(m, v[j]);
        m = waveMax(m);
        __syncthreads();
        if (lane == 0) red[w] = m;
        __syncthreads();
        m = fmaxf(fmaxf(red[0], red[1]), fmaxf(red[2], red[3]));

        float s = 0.f;
#pragma unroll
        for (int j = 0; j < 16; ++j) s += __expf(v[j] - m);
        s = waveSum(s);
        __syncthreads();
        if (lane == 0) red[w] = s;
        __syncthreads();
        s = red[0] + red[1] + red[2] + red[3];

        if (t == 0) stats[(b * 8 + h) * 64 + q] = make_float2(m, 1.f / s);
#pragma unroll
        for (int j = 0; j < 16; ++j) attnacc[j] += v[j];
    }
    float* arow = attns + (long)bq * 4096;
#pragma unroll
    for (int j = 0; j < 16; ++j) arow[kb + j] = attnacc[j] * 0.125f;  // /H
}

// ---------------------------------------------------------------------------
// split-K PV reduce: part (8,128,64,64) fp32 -> o16 (16,64,512) bf16
// ---------------------------------------------------------------------------
__global__ __launch_bounds__(256) void pv_reduce_k(
    const float* __restrict__ part, u16* __restrict__ o16)
{
    const int i = blockIdx.x * 256 + threadIdx.x;
    const int d4 = i & 15;
    const int q  = (i >> 4) & 63;
    const int bh = i >> 10;
    const float* p = part + (long)bh * 4096 + q * 64 + d4 * 4;
    float4 s = {0.f, 0.f, 0.f, 0.f};
#pragma unroll
    for (int sp = 0; sp < 8; ++sp) {
        const float4 v = *(const float4*)(p + (long)sp * 524288);
        s.x += v.x; s.y += v.y; s.z += v.z; s.w += v.w;
    }
    const int b = bh >> 3, h = bh & 7;
    u16* o = o16 + (long)b * 32768 + q * 512 + h * 64 + d4 * 4;
    short4v r;
    r[0] = (short)f2b(s.x); r[1] = (short)f2b(s.y);
    r[2] = (short)f2b(s.z); r[3] = (short)f2b(s.w);
    *(short4v*)o = r;
}

// split-K FF2 reduce + bias
__global__ __launch_bounds__(256) void ffred_k(
    const float* __restrict__ part, const float* __restrict__ bias,
    float* __restrict__ out)
{
    const int i = (blockIdx.x * 256 + threadIdx.x) * 4;
    const int c = i & 511;
    float4 s = *(const float4*)(part + i);
#pragma unroll
    for (int sp = 1; sp < 4; ++sp) {
        const float4 v = *(const float4*)(part + (long)sp * 524288 + i);
        s.x += v.x; s.y += v.y; s.z += v.z; s.w += v.w;
    }
    s.x += bias[c]; s.y += bias[c + 1]; s.z += bias[c + 2]; s.w += bias[c + 3];
    *(float4*)(out + i) = s;
}

// u[l][b][c'] = sum_c Wk[l][c'][c] * extra[b][c]
__global__ __launch_bounds__(256) void umat_k(
    const float* __restrict__ Wk, const float* __restrict__ extra,
    float* __restrict__ u)
{
    __shared__ float ex[16][512];
    const int l = blockIdx.x;
    const int t = threadIdx.x;
    for (int i = t; i < 16 * 512 / 4; i += 256)
        ((float4*)&ex[0][0])[i] = ((const float4*)extra)[i];
    __syncthreads();
    const int lane = t & 63, wave = t >> 6;
    const int row = blockIdx.y * 4 + wave;
    const float* wrow = Wk + ((size_t)l * 512 + row) * 512 + lane * 8;
    float w[8];
#pragma unroll
    for (int j = 0; j < 8; ++j) w[j] = wrow[j];
    float s[16];
#pragma unroll
    for (int b = 0; b < 16; ++b) {
        float x = 0.f;
#pragma unroll
        for (int j = 0; j < 8; ++j) x += w[j] * ex[b][lane * 8 + j];
        s[b] = waveSum(x);
    }
    if (lane < 16) u[((size_t)l * 16 + lane) * 512 + row] = s[lane];
}

// cb[l*16+b] = dot(extra[b], bk[l])
__global__ __launch_bounds__(256) void cbk_k(
    const float* __restrict__ bk, const float* __restrict__ extra,
    float* __restrict__ cb)
{
    const int gw = blockIdx.x * 4 + (threadIdx.x >> 6);
    const int lane = threadIdx.x & 63;
    const int l = gw >> 4, b = gw & 15;
    float s = 0.f;
#pragma unroll
    for (int j = 0; j < 8; ++j)
        s += extra[b * 512 + lane * 8 + j] * bk[l * 512 + lane * 8 + j];
    s = waveSum(s);
    if (lane == 0) cb[gw] = s;
}

// feat fp32 -> bf16, fused with aff for all 3 layers
__global__ __launch_bounds__(256) void cvt16_aff_k(
    const float* __restrict__ feat, u16* __restrict__ dst,
    const float* __restrict__ u, const float* __restrict__ cb,
    float* __restrict__ affb, float* __restrict__ affs_out)
{
    const int t = blockIdx.x * 256 + threadIdx.x;
    const long i = (long)t * 8;
    const int lane = threadIdx.x & 63;
    const int r = t >> 6;
    const int b = r >> 12;
    const float4 a0 = *(const float4*)(feat + i);
    const float4 a1 = *(const float4*)(feat + i + 4);
    short8 o;
    o[0] = (short)f2b(a0.x); o[1] = (short)f2b(a0.y);
    o[2] = (short)f2b(a0.z); o[3] = (short)f2b(a0.w);
    o[4] = (short)f2b(a1.x); o[5] = (short)f2b(a1.y);
    o[6] = (short)f2b(a1.z); o[7] = (short)f2b(a1.w);
    *(short8*)(dst + i) = o;
    const float f[8] = {a0.x, a0.y, a0.z, a0.w, a1.x, a1.y, a1.z, a1.w};
#pragma unroll
    for (int l = 0; l < 3; ++l) {
        const float* ur = u + ((size_t)l * 16 + b) * 512 + lane * 8;
        float s = 0.f;
#pragma unroll
        for (int j = 0; j < 8; ++j) s += f[j] * ur[j];
        s = waveSum(s);
        if (lane == 0) {
            const float av = 1.f / (1.f + __expf(-0.015625f * (s + cb[l * 16 + b])));
            affb[l * 65536 + r] = av;
            affs_out[l * 65536 + r] = av;
        }
    }
}

// x = LN(x + add; g, beta)
template<bool WRITE_OUT>
__global__ __launch_bounds__(256) void ln_k(
    float* __restrict__ x, const float* __restrict__ add,
    const float* __restrict__ g, const float* __restrict__ be,
    u16* __restrict__ x16, float* __restrict__ outp)
{
    const int r = blockIdx.x, t = threadIdx.x;
    const int w = t >> 6, lane = t & 63;
    __shared__ float red[4];
    float* xr = x + (long)r * 512;
    const float* ar = add + (long)r * 512;
    const float v0 = xr[2 * t]     + ar[2 * t];
    const float v1 = xr[2 * t + 1] + ar[2 * t + 1];
    float s = waveSum(v0 + v1);
    if (lane == 0) red[w] = s;
    __syncthreads();
    s = red[0] + red[1] + red[2] + red[3];
    const float mu = s * (1.f / 512.f);
    const float d0 = v0 - mu, d1 = v1 - mu;
    __syncthreads();
    float vs = waveSum(d0 * d0 + d1 * d1);
    if (lane == 0) red[w] = vs;
    __syncthreads();
    vs = red[0] + red[1] + red[2] + red[3];
    const float rs = rsqrtf(vs * (1.f / 512.f) + 1e-5f);
    const float o0 = g[2 * t]     * d0 * rs + be[2 * t];
    const float o1 = g[2 * t + 1] * d1 * rs + be[2 * t + 1];
    xr[2 * t] = o0; xr[2 * t + 1] = o1;
    x16[(long)r * 512 + 2 * t]     = f2b(o0);
    x16[(long)r * 512 + 2 * t + 1] = f2b(o1);
    if constexpr (WRITE_OUT) {
        outp[(long)r * 512 + 2 * t]     = o0;
        outp[(long)r * 512 + 2 * t + 1] = o1;
    }
}

// x = copy(queries) fp32 + bf16
__global__ __launch_bounds__(256) void initx_k(
    const float* __restrict__ src, float* __restrict__ x, u16* __restrict__ x16)
{
    const long i = ((long)blockIdx.x * 256 + threadIdx.x) * 8;
    const float4 a = *(const float4*)(src + i);
    const float4 b = *(const float4*)(src + i + 4);
    *(float4*)(x + i) = a;
    *(float4*)(x + i + 4) = b;
    short8 r;
    r[0] = (short)f2b(a.x); r[1] = (short)f2b(a.y); r[2] = (short)f2b(a.z); r[3] = (short)f2b(a.w);
    r[4] = (short)f2b(b.x); r[5] = (short)f2b(b.y); r[6] = (short)f2b(b.z); r[7] = (short)f2b(b.w);
    *(short8*)(x16 + i) = r;
}

// W (K,N) fp32 -> WT (N,K) bf16, batched over blockIdx.z
__global__ __launch_bounds__(256) void transpose_w_k(
    const float* __restrict__ W, u16* __restrict__ WT, int K, int N)
{
    __shared__ float tile[32][33];
    const int z = blockIdx.z;
    W  += (size_t)z * K * N;
    WT += (size_t)z * K * N;
    const int n0 = blockIdx.x * 32, k0 = blockIdx.y * 32;
    const int tx = threadIdx.x & 31, ty = threadIdx.x >> 5;
#pragma unroll
    for (int j = 0; j < 32; j += 8)
        tile[ty + j][tx] = W[(size_t)(k0 + ty + j) * N + n0 + tx];
    __syncthreads();
#pragma unroll
    for (int j = 0; j < 32; j += 8)
        WT[(size_t)(n0 + ty + j) * K + k0 + tx] = f2b(tile[tx][ty + j]);
}

// ---------------------------------------------------------------------------
extern "C" void kernel_launch(void* const* d_in, const int* in_sizes, int n_in,
                              void* d_out, int out_size, void* d_ws, size_t ws_size,
                              hipStream_t stream)
{
    (void)in_sizes; (void)n_in; (void)out_size; (void)ws_size;
    const float* queries = (const float*)d_in[0];
    const float* feat    = (const float*)d_in[1];
    const float* extra   = (const float*)d_in[2];
    const float* Wq = (const float*)d_in[3];  const float* bq = (const float*)d_in[4];
    const float* Wk = (const float*)d_in[5];  const float* bk = (const float*)d_in[6];
    const float* Wv = (const float*)d_in[7];  const float* bv = (const float*)d_in[8];
    const float* Wo = (const float*)d_in[9];  const float* bo = (const float*)d_in[10];
    const float* W1 = (const float*)d_in[11]; const float* b1 = (const float*)d_in[12];
    const float* W2 = (const float*)d_in[13]; const float* b2 = (const float*)d_in[14];
    const float* g2 = (const float*)d_in[15]; const float* be2 = (const float*)d_in[16];
    const float* g3 = (const float*)d_in[17]; const float* be3 = (const float*)d_in[18];

    char* wsb = (char*)d_ws;
    size_t off = 0;
    auto alloc = [&](size_t bytes) -> char* {
        char* p = wsb + off; off += (bytes + 255) & ~(size_t)255; return p;
    };
    u16*  feat16 = (u16*)alloc(33554432ull * 2);   // (B*Nk, C) bf16
    u16*  WqT = (u16*)alloc(786432ull * 2);        // (L,512,512) transposed
    u16*  WkT = (u16*)alloc(786432ull * 2);
    u16*  WvT = (u16*)alloc(786432ull * 2);
    u16*  WoT = (u16*)alloc(786432ull * 2);
    u16*  W1T = (u16*)alloc(3145728ull * 2);       // (L,2048,512)
    u16*  W2T = (u16*)alloc(3145728ull * 2);       // (L,512,2048)
    u16*  K16 = (u16*)alloc(33554432ull * 2);      // (B,Nk,C); later PV partials
    u16*  VT16 = (u16*)alloc(33554432ull * 2);     // (B,C,Nk) aff-gated; later FF2 partials
    u16*  q16 = (u16*)alloc(524288ull * 2);        // (B*Nq, C)
    u16*  S16 = (u16*)alloc(33554432ull * 2);      // (B,H,64,4096) scores*SCALE
    float* affb  = (float*)alloc(196608ull * 4);   // (L,B,Nk)
    u16*  o16 = (u16*)alloc(524288ull * 2);        // attention out (B,Nq,C)
    float* oproj = (float*)alloc(524288ull * 4);
    float* xb    = (float*)alloc(524288ull * 4);
    u16*  x16 = (u16*)alloc(524288ull * 2);
    u16*  h116 = (u16*)alloc(2097152ull * 2);      // (B*Nq, 2048)
    float* ffb   = (float*)alloc(524288ull * 4);
    float* uvec  = (float*)alloc(24576ull * 4);    // (L,16,512)
    float* cb    = (float*)alloc(48ull * 4);
    float2* stats = (float2*)alloc(8192ull * 8);   // (B*H*64) {m, 1/sum}
    float* partPV = (float*)K16;                   // alias: K dead after S-GEMM
    float* part2  = (float*)VT16;                  // alias: VT dead after PV

    float* out_f = (float*)d_out;
    float* outs_base  = out_f;                     // (3,16,64,512)
    float* attns_base = out_f + 1572864;           // (3,16,64,4096)
    float* affs_base  = out_f + 14155776;          // (3,16,1,1,4096)

    // prep (layer-independent)
    umat_k<<<dim3(3, 128), 256, 0, stream>>>(Wk, extra, uvec);
    cbk_k<<<12, 256, 0, stream>>>(bk, extra, cb);
    cvt16_aff_k<<<16384, 256, 0, stream>>>(feat, feat16, uvec, cb, affb, affs_base);
    initx_k<<<256, 256, 0, stream>>>(queries, xb, x16);
    transpose_w_k<<<dim3(16, 16, 3), 256, 0, stream>>>(Wq, WqT, 512, 512);
    transpose_w_k<<<dim3(16, 16, 3), 256, 0, stream>>>(Wk, WkT, 512, 512);
    transpose_w_k<<<dim3(16, 16, 3), 256, 0, stream>>>(Wv, WvT, 512, 512);
    transpose_w_k<<<dim3(16, 16, 3), 256, 0, stream>>>(Wo, WoT, 512, 512);
    transpose_w_k<<<dim3(64, 16, 3), 256, 0, stream>>>(W1, W1T, 512, 2048);
    transpose_w_k<<<dim3(16, 64, 3), 256, 0, stream>>>(W2, W2T, 2048, 512);

    for (int i = 0; i < 3; ++i) {
        // K = feat @ Wk + bk   (M=65536, N=512, K=512) -> bf16 (B,Nk,C)
        gemm256x256_k<false, true, false><<<dim3(2, 256, 1), 512, 0, stream>>>(
            feat16, WkT + i * 262144, bk + i * 512, K16,
            512, 512, 512, 0, 0, 0, nullptr);
        // VT'[b] = aff ⊙ ((feat[b] @ Wv)^T + bv)  -> (B,C,Nk)
        gemm256x256_k<true, true, true><<<dim3(16, 2, 16), 512, 0, stream>>>(
            WvT + i * 262144, feat16, bv + i * 512, VT16,
            512, 512, 4096, 0, 2097152, 2097152, affb + i * 65536);
        // q = x @ Wq + bq  (1024 x 512)
        gemm_bt_k<64, 64, true, false, false, true, false, false>
            <<<dim3(8, 16, 1), 256, 0, stream>>>(
            x16, WqT + i * 262144, bq + i * 512, q16,
            512, 512, 512, 512, 1, 0, 0, 0, 0, 0, 0, 1.f, nullptr, nullptr);
        // S[b,h] = SCALE * q_h @ K_h^T   (batch 128: M=64,N=4096,K=64)
        gemm_bt_k<64, 128, true, false, false, false, false, false>
            <<<dim3(32, 1, 128), 256, 0, stream>>>(
            q16, K16, nullptr, S16,
            64, 512, 512, 4096, 8, 32768, 64, 2097152, 64, 2097152, 262144,
            0.125f, nullptr, nullptr);
        // softmax stats + attns
        smstats_k<<<1024, 256, 0, stream>>>(
            S16, stats, attns_base + (size_t)i * 4194304);
        // o[b,h] = softmax(S) @ V', split-K 8, softmax fused at fragment load
        gemm_bt_k<64, 64, false, false, false, false, false, true>
            <<<dim3(1, 1, 1024), 256, 0, stream>>>(
            S16, VT16, nullptr, partPV,
            512, 4096, 4096, 64, 128, 512, 262144, 512, 262144, 524288, 4096,
            1.f, nullptr, stats);
        pv_reduce_k<<<512, 256, 0, stream>>>(partPV, o16);
        // o @ Wo + bo -> fp32
        gemm_bt_k<64, 64, false, false, false, true, false, false>
            <<<dim3(8, 16, 1), 256, 0, stream>>>(
            o16, WoT + i * 262144, bo + i * 512, oproj,
            512, 512, 512, 512, 1, 0, 0, 0, 0, 0, 0, 1.f, nullptr, nullptr);
        // x = LN(x + oproj; g2, beta2)
        ln_k<false><<<1024, 256, 0, stream>>>(xb, oproj, g2 + i * 512, be2 + i * 512, x16, nullptr);
        // h1 = relu(x @ W1 + b1) -> bf16 (1024 x 2048)
        gemm_bt_k<64, 128, true, true, false, true, false, false>
            <<<dim3(16, 16, 1), 256, 0, stream>>>(
            x16, W1T + (size_t)i * 1048576, b1 + i * 2048, h116,
            512, 512, 512, 2048, 1, 0, 0, 0, 0, 0, 0, 1.f, nullptr, nullptr);
        // ff partials = h1 @ W2 (split-K 4) -> fp32 (4,1024,512)
        gemm_bt_k<64, 64, false, false, false, false, false, false>
            <<<dim3(8, 16, 4), 256, 0, stream>>>(
            h116, W2T + (size_t)i * 1048576, nullptr, part2,
            512, 2048, 2048, 512, 1, 512, 0, 512, 0, 524288, 0,
            1.f, nullptr, nullptr);
        ffred_k<<<512, 256, 0, stream>>>(part2, b2 + i * 512, ffb);
        // x = LN(x + ff; g3, beta3), write outs[i]
        ln_k<true><<<1024, 256, 0, stream>>>(xb, ffb, g3 + i * 512, be3 + i * 512, x16,
                                             outs_base + (size_t)i * 524288);
    }
}

// Round 9
// 670.057 us; speedup vs baseline: 1.6644x; 1.1600x over previous
//
#include <hip/hip_runtime.h>

// SegDecoder: 3-layer cross-attention decoder on MI355X (gfx950).
// B=16, Nq=64, Nk=4096, C=512, H=8, hd=64, FF=2048, L=3.
// R9: attention flash-fused. attns = (SCALE/H) q_full @ K_full^T (one GEMM,
// head-sum identity). S never materialized: fattn_k does per-(b,h,kv/4)
// online-softmax QK^T->PV with (m,l,O) partials + merge kernel.
// Kproj/VT keep R8's 256^2 + XCD swizzle (proven -40us).

typedef unsigned short u16;
typedef __attribute__((ext_vector_type(8))) short short8;
typedef __attribute__((ext_vector_type(4))) short short4v;
typedef __attribute__((ext_vector_type(4))) float f32x4;

__device__ __forceinline__ float b2f(u16 u) {
    union { unsigned int i; float f; } v; v.i = ((unsigned int)u) << 16; return v.f;
}
__device__ __forceinline__ u16 f2b(float f) {  // round-to-nearest-even
    unsigned int x = __float_as_uint(f);
    x += 0x7fffu + ((x >> 16) & 1u);
    return (u16)(x >> 16);
}

__device__ __forceinline__ float waveSum(float v) {
#pragma unroll
    for (int o = 32; o > 0; o >>= 1) v += __shfl_xor(v, o);
    return v;
}

// async global->LDS, 16B per lane. LDS dest is wave-uniform base + lane*16.
__device__ __forceinline__ void gl_lds16(const void* g, void* l) {
    __builtin_amdgcn_global_load_lds(
        (__attribute__((address_space(1))) void*)g,
        (__attribute__((address_space(3))) void*)l, 16, 0, 0);
}

// ---------------------------------------------------------------------------
// Flash attention partial: block = (split, bh). 1024 keys per split, tiles of
// 128. Q (64x64) LDS-resident; per tile: stage K(128x64) + V(64x128, VT rows),
// S = Q@K^T in-register (16 MFMA/wave), s *= SCALE, online softmax (m,l),
// P->bf16->LDS (XOR-swizzled), O += P@V (16 MFMA). Outputs unnormalized O +
// (m,l). 4 waves; wave w owns q rows [w*16, w*16+16).
// ---------------------------------------------------------------------------
__global__ __launch_bounds__(256) void fattn_k(
    const u16* __restrict__ q16, const u16* __restrict__ K16,
    const u16* __restrict__ VT16, float* __restrict__ Op,
    float2* __restrict__ ml)
{
    __shared__ u16 Qs[64][64];    // 8KB
    __shared__ u16 Ks[128][64];   // 16KB
    __shared__ u16 Vs[64][128];   // 16KB
    __shared__ u16 Ps[64][128];   // 16KB  (56KB total)
    const int t = threadIdx.x;
    const int lane = t & 63;
    const int w = t >> 6;                 // wave 0..3
    const int bh = blockIdx.y;            // b*8+h
    const int split = blockIdx.x;         // 0..3
    const int b = bh >> 3, h = bh & 7;
    const int kbase = split * 1024;
    const int rl = lane & 15, uq = lane >> 4;
    const int r0 = (lane >> 4) * 4;
    const int c0 = lane & 15;
    const int srow8 = lane >> 3, up8 = lane & 7;     // 128B-row staging
    const int srow4 = lane >> 4, up16 = lane & 15;   // 256B-row staging

    // stage Q once (row = q, 128B segment at col h*64)
#pragma unroll
    for (int rnd = 0; rnd < 2; ++rnd) {
        const int row = rnd * 32 + w * 8 + srow8;
        const int ul = up8 ^ (row & 7);
        gl_lds16(q16 + ((long)(b * 64 + row)) * 512 + h * 64 + ul * 8,
                 &Qs[rnd * 32 + w * 8][0]);
    }

    f32x4 O[4];
#pragma unroll
    for (int n = 0; n < 4; ++n) O[n] = (f32x4){0.f, 0.f, 0.f, 0.f};
    float m_run[4] = {-3.0e38f, -3.0e38f, -3.0e38f, -3.0e38f};
    float l_run[4] = {0.f, 0.f, 0.f, 0.f};

    const int R = w * 16 + rl;   // A-frag row (this lane's q row)

    for (int tt = 0; tt < 8; ++tt) {
        __syncthreads();   // prev-tile LDS reads done (covers Q stage too)
#pragma unroll
        for (int rnd = 0; rnd < 4; ++rnd) {          // K tile 128x64
            const int row = rnd * 32 + w * 8 + srow8;
            const int ul = up8 ^ (row & 7);
            gl_lds16(K16 + ((long)(b * 4096 + kbase + tt * 128 + row)) * 512
                         + h * 64 + ul * 8,
                     &Ks[rnd * 32 + w * 8][0]);
        }
#pragma unroll
        for (int rnd = 0; rnd < 4; ++rnd) {          // V tile 64x128 (VT rows)
            const int row = rnd * 16 + w * 4 + srow4;
            const int ul = up16 ^ (row & 15);
            gl_lds16(VT16 + (long)b * 2097152 + ((long)(h * 64 + row)) * 4096
                         + kbase + tt * 128 + ul * 8,
                     &Vs[rnd * 16 + w * 4][0]);
        }
        __syncthreads();   // loads landed

        // S = Q @ K^T : 16 q-rows x 128 k-cols per wave, K=64
        f32x4 s[8];
        short8 af[2];
#pragma unroll
        for (int kc = 0; kc < 2; ++kc)
            af[kc] = *(const short8*)(&Qs[R][((kc * 4 + uq) ^ (R & 7)) * 8]);
#pragma unroll
        for (int j = 0; j < 8; ++j) {
            s[j] = (f32x4){0.f, 0.f, 0.f, 0.f};
            const int Rb = j * 16 + rl;
#pragma unroll
            for (int kc = 0; kc < 2; ++kc) {
                short8 bf = *(const short8*)(&Ks[Rb][((kc * 4 + uq) ^ (Rb & 7)) * 8]);
                s[j] = __builtin_amdgcn_mfma_f32_16x16x32_bf16(af[kc], bf, s[j], 0, 0, 0);
            }
        }
#pragma unroll
        for (int j = 0; j < 8; ++j)
#pragma unroll
            for (int r = 0; r < 4; ++r) s[j][r] *= 0.125f;   // SCALE

        // online softmax
        float mv[4];
#pragma unroll
        for (int r = 0; r < 4; ++r) {
            float m = s[0][r];
#pragma unroll
            for (int j = 1; j < 8; ++j) m = fmaxf(m, s[j][r]);
#pragma unroll
            for (int mask = 1; mask < 16; mask <<= 1)
                m = fmaxf(m, __shfl_xor(m, mask));
            mv[r] = m;
        }
        float al[4], rs[4];
#pragma unroll
        for (int r = 0; r < 4; ++r) {
            const float mn = fmaxf(m_run[r], mv[r]);
            al[r] = __expf(m_run[r] - mn);
            m_run[r] = mn;
            rs[r] = 0.f;
        }
#pragma unroll
        for (int j = 0; j < 8; ++j)
#pragma unroll
            for (int r = 0; r < 4; ++r) {
                s[j][r] = __expf(s[j][r] - m_run[r]);
                rs[r] += s[j][r];
            }
#pragma unroll
        for (int r = 0; r < 4; ++r) {
#pragma unroll
            for (int mask = 1; mask < 16; mask <<= 1)
                rs[r] += __shfl_xor(rs[r], mask);
            l_run[r] = l_run[r] * al[r] + rs[r];
        }
#pragma unroll
        for (int n = 0; n < 4; ++n)
#pragma unroll
            for (int r = 0; r < 4; ++r) O[n][r] *= al[r];

        // P -> bf16 -> Ps (row=q, col=k; unit = col>>3, phys = unit^(row&15))
#pragma unroll
        for (int j = 0; j < 8; ++j)
#pragma unroll
            for (int r = 0; r < 4; ++r) {
                const int row = w * 16 + r0 + r;
                const int col = j * 16 + c0;
                Ps[row][(((col >> 3) ^ (row & 15)) << 3) + (col & 7)] = f2b(s[j][r]);
            }
        // O += P @ V (same-wave Ps; compiler inserts lgkmcnt)
#pragma unroll
        for (int kc4 = 0; kc4 < 4; ++kc4) {
            const short8 afp = *(const short8*)(&Ps[R][(((kc4 * 4 + uq) ^ (R & 15)) << 3)]);
#pragma unroll
            for (int n = 0; n < 4; ++n) {
                const int Rv = n * 16 + rl;
                const short8 bfv = *(const short8*)(&Vs[Rv][(((kc4 * 4 + uq) ^ (Rv & 15)) << 3)]);
                O[n] = __builtin_amdgcn_mfma_f32_16x16x32_bf16(afp, bfv, O[n], 0, 0, 0);
            }
        }
    }

    const long obase = ((long)(split * 128 + bh)) * 64;
#pragma unroll
    for (int n = 0; n < 4; ++n)
#pragma unroll
        for (int r = 0; r < 4; ++r) {
            const int q = w * 16 + r0 + r;
            Op[(obase + q) * 64 + n * 16 + c0] = O[n][r];
        }
    if (c0 == 0) {
#pragma unroll
        for (int r = 0; r < 4; ++r) {
            const int q = w * 16 + r0 + r;
            ml[obase + q] = make_float2(m_run[r], l_run[r]);
        }
    }
}

// merge 4 flash splits -> o16 (B,Nq,C)
__global__ __launch_bounds__(256) void fmerge_k(
    const float* __restrict__ Op, const float2* __restrict__ ml,
    u16* __restrict__ o16)
{
    const int i = blockIdx.x * 256 + threadIdx.x;   // 131072
    const int d4 = i & 15;
    const int q  = (i >> 4) & 63;
    const int bh = i >> 10;
    const float2 m0 = ml[((long)(0 * 128 + bh)) * 64 + q];
    const float2 m1 = ml[((long)(1 * 128 + bh)) * 64 + q];
    const float2 m2 = ml[((long)(2 * 128 + bh)) * 64 + q];
    const float2 m3 = ml[((long)(3 * 128 + bh)) * 64 + q];
    const float m = fmaxf(fmaxf(m0.x, m1.x), fmaxf(m2.x, m3.x));
    const float e0 = __expf(m0.x - m), e1 = __expf(m1.x - m);
    const float e2 = __expf(m2.x - m), e3 = __expf(m3.x - m);
    const float inv = 1.f / (m0.y * e0 + m1.y * e1 + m2.y * e2 + m3.y * e3);
    const float4 v0 = *(const float4*)(Op + (((long)(0 * 128 + bh)) * 64 + q) * 64 + d4 * 4);
    const float4 v1 = *(const float4*)(Op + (((long)(1 * 128 + bh)) * 64 + q) * 64 + d4 * 4);
    const float4 v2 = *(const float4*)(Op + (((long)(2 * 128 + bh)) * 64 + q) * 64 + d4 * 4);
    const float4 v3 = *(const float4*)(Op + (((long)(3 * 128 + bh)) * 64 + q) * 64 + d4 * 4);
    float4 acc;
    acc.x = (v0.x * e0 + v1.x * e1 + v2.x * e2 + v3.x * e3) * inv;
    acc.y = (v0.y * e0 + v1.y * e1 + v2.y * e2 + v3.y * e3) * inv;
    acc.z = (v0.z * e0 + v1.z * e1 + v2.z * e2 + v3.z * e3) * inv;
    acc.w = (v0.w * e0 + v1.w * e1 + v2.w * e2 + v3.w * e3) * inv;
    const int b = bh >> 3, h = bh & 7;
    short4v r;
    r[0] = (short)f2b(acc.x); r[1] = (short)f2b(acc.y);
    r[2] = (short)f2b(acc.z); r[3] = (short)f2b(acc.w);
    *(short4v*)(o16 + (long)b * 32768 + q * 512 + h * 64 + d4 * 4) = r;
}

// ---------------------------------------------------------------------------
// Big-GEMM (Kproj / VT): 256x256 tile, BK=64, 8 waves, 2-buf stage-first,
// XCD-chunk swizzle. (R8)
// ---------------------------------------------------------------------------
template<bool BIAS_ROW, bool HAS_BIAS, bool AFFC>
__global__ __launch_bounds__(512, 1) void gemm256x256_k(
    const u16* __restrict__ A, const u16* __restrict__ Bt,
    const float* __restrict__ bias, u16* __restrict__ Cout,
    int lda, int ldb, int ldc, long sA2, long sB2, long sC2,
    const float* __restrict__ affc)
{
    __shared__ u16 As[2][256][64];
    __shared__ u16 Bs[2][256][64];
    const int t = threadIdx.x;
    const int lane = t & 63;
    const int wave = t >> 6;

    const int gx = gridDim.x, gy = gridDim.y;
    const int nwg = gx * gy * gridDim.z;
    int id;
    {
        const int orig = blockIdx.x + blockIdx.y * gx + blockIdx.z * gx * gy;
        const int qq = nwg >> 3, rr = nwg & 7;
        const int xcd = orig & 7, sub = orig >> 3;
        id = (xcd < rr ? xcd * (qq + 1) : rr * (qq + 1) + (xcd - rr) * qq) + sub;
    }
    const int bx = id % gx;
    const int by = (id / gx) % gy;
    const int z  = id / (gx * gy);

    A  += (long)z * sA2;
    Bt += (long)z * sB2;
    const long cbase = (long)z * sC2;
    const int n0 = bx * 256;
    const int m0 = by * 256;
    const int wm = wave >> 2;
    const int wn = wave & 3;
    const int rl = lane & 15, uq = lane >> 4;
    const int srow = lane >> 3;
    const int up   = lane & 7;

    f32x4 acc[8][4];
#pragma unroll
    for (int i = 0; i < 8; ++i)
#pragma unroll
        for (int j = 0; j < 4; ++j) acc[i][j] = (f32x4){0.f, 0.f, 0.f, 0.f};

    auto stage = [&](int buf, int kt) {
        const int k0 = kt * 64;
#pragma unroll
        for (int r = 0; r < 4; ++r) {
            const int row = r * 64 + wave * 8 + srow;
            const int ul = up ^ (row & 7);
            gl_lds16(A + (long)(m0 + row) * lda + k0 + ul * 8,
                     &As[buf][r * 64 + wave * 8][0]);
        }
#pragma unroll
        for (int r = 0; r < 4; ++r) {
            const int row = r * 64 + wave * 8 + srow;
            const int ul = up ^ (row & 7);
            gl_lds16(Bt + (long)(n0 + row) * ldb + k0 + ul * 8,
                     &Bs[buf][r * 64 + wave * 8][0]);
        }
    };

    auto compute = [&](int buf) {
#pragma unroll
        for (int kc = 0; kc < 2; ++kc) {
            short8 af[8], bf[4];
#pragma unroll
            for (int i = 0; i < 8; ++i) {
                const int R = wm * 128 + i * 16 + rl;
                af[i] = *(const short8*)(&As[buf][R][((kc * 4 + uq) ^ (R & 7)) * 8]);
            }
#pragma unroll
            for (int j = 0; j < 4; ++j) {
                const int R = wn * 64 + j * 16 + rl;
                bf[j] = *(const short8*)(&Bs[buf][R][((kc * 4 + uq) ^ (R & 7)) * 8]);
            }
            __builtin_amdgcn_s_setprio(1);
#pragma unroll
            for (int i = 0; i < 8; ++i)
#pragma unroll
                for (int j = 0; j < 4; ++j)
                    acc[i][j] = __builtin_amdgcn_mfma_f32_16x16x32_bf16(
                        af[i], bf[j], acc[i][j], 0, 0, 0);
            __builtin_amdgcn_s_setprio(0);
        }
    };

    stage(0, 0);
    __syncthreads();
    int buf = 0;
#pragma unroll
    for (int kt = 0; kt < 8; ++kt) {
        if (kt + 1 < 8) stage(buf ^ 1, kt + 1);
        compute(buf);
        __syncthreads();
        buf ^= 1;
    }

    const int r0 = (lane >> 4) * 4;
    const int c0 = lane & 15;
#pragma unroll
    for (int i = 0; i < 8; ++i) {
#pragma unroll
        for (int j = 0; j < 4; ++j) {
#pragma unroll
            for (int r = 0; r < 4; ++r) {
                const int row = m0 + wm * 128 + i * 16 + r0 + r;
                const int col = n0 + wn * 64 + j * 16 + c0;
                float v = acc[i][j][r];
                if constexpr (HAS_BIAS) {
                    if constexpr (BIAS_ROW) v += bias[row]; else v += bias[col];
                }
                if constexpr (AFFC) v *= affc[(long)z * 4096 + col];
                Cout[cbase + (long)row * ldc + col] = f2b(v);
            }
        }
    }
}

// ---------------------------------------------------------------------------
// Generic batched GEMM: C = alpha*A@Bt^T [+bias][relu]; BK=64 single-buffered.
// ---------------------------------------------------------------------------
template<int TM, int TN, bool OUT_BF16, bool RELU, bool BIAS_ROW, bool HAS_BIAS>
__global__ __launch_bounds__(256) void gemm_bt_k(
    const u16* __restrict__ A, const u16* __restrict__ Bt,
    const float* __restrict__ bias, void* __restrict__ Cout,
    int K, int lda, int ldb, int ldc,
    long sA1, long sB1, long sC1, float alpha)
{
    __shared__ u16 As[TM][64];
    __shared__ u16 Bs[TN][64];
    const int t = threadIdx.x;
    const int lane = t & 63;
    const int wave = t >> 6;
    const int z = blockIdx.z;
    A  += (long)z * sA1;
    Bt += (long)z * sB1;
    const long cbase = (long)z * sC1;
    const int n0 = blockIdx.x * TN;
    const int m0 = blockIdx.y * TM;
    constexpr int FM = TM / 32, FN = TN / 32;
    const int wr = wave >> 1, wc = wave & 1;
    const int rl = lane & 15, uq = lane >> 4;

    f32x4 acc[FM][FN];
#pragma unroll
    for (int i = 0; i < FM; ++i)
#pragma unroll
        for (int j = 0; j < FN; ++j) acc[i][j] = (f32x4){0.f, 0.f, 0.f, 0.f};

    const int srow = lane >> 3;
    const int up   = lane & 7;

    for (int k0 = 0; k0 < K; k0 += 64) {
        __syncthreads();
#pragma unroll
        for (int r = 0; r < TM / 32; ++r) {
            const int br = (wave * (TM / 32) + r) * 8;
            const int row = br + srow;
            const int ul = up ^ (row & 7);
            gl_lds16(A + (long)(m0 + row) * lda + k0 + ul * 8, &As[br][0]);
        }
#pragma unroll
        for (int r = 0; r < TN / 32; ++r) {
            const int br = (wave * (TN / 32) + r) * 8;
            const int row = br + srow;
            const int ul = up ^ (row & 7);
            gl_lds16(Bt + (long)(n0 + row) * ldb + k0 + ul * 8, &Bs[br][0]);
        }
        __syncthreads();

#pragma unroll
        for (int kc = 0; kc < 2; ++kc) {
            short8 af[FM], bf[FN];
#pragma unroll
            for (int i = 0; i < FM; ++i) {
                const int R = wr * (TM / 2) + i * 16 + rl;
                af[i] = *(const short8*)(&As[R][((kc * 4 + uq) ^ (R & 7)) * 8]);
            }
#pragma unroll
            for (int j = 0; j < FN; ++j) {
                const int R = wc * (TN / 2) + j * 16 + rl;
                bf[j] = *(const short8*)(&Bs[R][((kc * 4 + uq) ^ (R & 7)) * 8]);
            }
#pragma unroll
            for (int i = 0; i < FM; ++i)
#pragma unroll
                for (int j = 0; j < FN; ++j)
                    acc[i][j] = __builtin_amdgcn_mfma_f32_16x16x32_bf16(
                        af[i], bf[j], acc[i][j], 0, 0, 0);
        }
    }

    const int r0 = (lane >> 4) * 4;
    const int c0 = lane & 15;
#pragma unroll
    for (int i = 0; i < FM; ++i) {
#pragma unroll
        for (int j = 0; j < FN; ++j) {
#pragma unroll
            for (int r = 0; r < 4; ++r) {
                const int row = m0 + wr * (TM / 2) + i * 16 + r0 + r;
                const int col = n0 + wc * (TN / 2) + j * 16 + c0;
                float v = acc[i][j][r] * alpha;
                if constexpr (HAS_BIAS) {
                    if constexpr (BIAS_ROW) v += bias[row]; else v += bias[col];
                }
                if constexpr (RELU) v = fmaxf(v, 0.f);
                const long idx = cbase + (long)row * ldc + col;
                if constexpr (OUT_BF16) ((u16*)Cout)[idx] = f2b(v);
                else                    ((float*)Cout)[idx] = v;
            }
        }
    }
}

// split-K FF2 reduce + bias
__global__ __launch_bounds__(256) void ffred_k(
    const float* __restrict__ part, const float* __restrict__ bias,
    float* __restrict__ out)
{
    const int i = (blockIdx.x * 256 + threadIdx.x) * 4;
    const int c = i & 511;
    float4 s = *(const float4*)(part + i);
#pragma unroll
    for (int sp = 1; sp < 4; ++sp) {
        const float4 v = *(const float4*)(part + (long)sp * 524288 + i);
        s.x += v.x; s.y += v.y; s.z += v.z; s.w += v.w;
    }
    s.x += bias[c]; s.y += bias[c + 1]; s.z += bias[c + 2]; s.w += bias[c + 3];
    *(float4*)(out + i) = s;
}

// u[l][b][c'] = sum_c Wk[l][c'][c] * extra[b][c]
__global__ __launch_bounds__(256) void umat_k(
    const float* __restrict__ Wk, const float* __restrict__ extra,
    float* __restrict__ u)
{
    __shared__ float ex[16][512];
    const int l = blockIdx.x;
    const int t = threadIdx.x;
    for (int i = t; i < 16 * 512 / 4; i += 256)
        ((float4*)&ex[0][0])[i] = ((const float4*)extra)[i];
    __syncthreads();
    const int lane = t & 63, wave = t >> 6;
    const int row = blockIdx.y * 4 + wave;
    const float* wrow = Wk + ((size_t)l * 512 + row) * 512 + lane * 8;
    float w[8];
#pragma unroll
    for (int j = 0; j < 8; ++j) w[j] = wrow[j];
    float s[16];
#pragma unroll
    for (int b = 0; b < 16; ++b) {
        float x = 0.f;
#pragma unroll
        for (int j = 0; j < 8; ++j) x += w[j] * ex[b][lane * 8 + j];
        s[b] = waveSum(x);
    }
    if (lane < 16) u[((size_t)l * 16 + lane) * 512 + row] = s[lane];
}

// cb[l*16+b] = dot(extra[b], bk[l])
__global__ __launch_bounds__(256) void cbk_k(
    const float* __restrict__ bk, const float* __restrict__ extra,
    float* __restrict__ cb)
{
    const int gw = blockIdx.x * 4 + (threadIdx.x >> 6);
    const int lane = threadIdx.x & 63;
    const int l = gw >> 4, b = gw & 15;
    float s = 0.f;
#pragma unroll
    for (int j = 0; j < 8; ++j)
        s += extra[b * 512 + lane * 8 + j] * bk[l * 512 + lane * 8 + j];
    s = waveSum(s);
    if (lane == 0) cb[gw] = s;
}

// feat fp32 -> bf16, fused with aff for all 3 layers
__global__ __launch_bounds__(256) void cvt16_aff_k(
    const float* __restrict__ feat, u16* __restrict__ dst,
    const float* __restrict__ u, const float* __restrict__ cb,
    float* __restrict__ affb, float* __restrict__ affs_out)
{
    const int t = blockIdx.x * 256 + threadIdx.x;
    const long i = (long)t * 8;
    const int lane = threadIdx.x & 63;
    const int r = t >> 6;
    const int b = r >> 12;
    const float4 a0 = *(const float4*)(feat + i);
    const float4 a1 = *(const float4*)(feat + i + 4);
    short8 o;
    o[0] = (short)f2b(a0.x); o[1] = (short)f2b(a0.y);
    o[2] = (short)f2b(a0.z); o[3] = (short)f2b(a0.w);
    o[4] = (short)f2b(a1.x); o[5] = (short)f2b(a1.y);
    o[6] = (short)f2b(a1.z); o[7] = (short)f2b(a1.w);
    *(short8*)(dst + i) = o;
    const float f[8] = {a0.x, a0.y, a0.z, a0.w, a1.x, a1.y, a1.z, a1.w};
#pragma unroll
    for (int l = 0; l < 3; ++l) {
        const float* ur = u + ((size_t)l * 16 + b) * 512 + lane * 8;
        float s = 0.f;
#pragma unroll
        for (int j = 0; j < 8; ++j) s += f[j] * ur[j];
        s = waveSum(s);
        if (lane == 0) {
            const float av = 1.f / (1.f + __expf(-0.015625f * (s + cb[l * 16 + b])));
            affb[l * 65536 + r] = av;
            affs_out[l * 65536 + r] = av;
        }
    }
}

// x = LN(x + add; g, beta)
template<bool WRITE_OUT>
__global__ __launch_bounds__(256) void ln_k(
    float* __restrict__ x, const float* __restrict__ add,
    const float* __restrict__ g, const float* __restrict__ be,
    u16* __restrict__ x16, float* __restrict__ outp)
{
    const int r = blockIdx.x, t = threadIdx.x;
    const int w = t >> 6, lane = t & 63;
    __shared__ float red[4];
    float* xr = x + (long)r * 512;
    const float* ar = add + (long)r * 512;
    const float v0 = xr[2 * t]     + ar[2 * t];
    const float v1 = xr[2 * t + 1] + ar[2 * t + 1];
    float s = waveSum(v0 + v1);
    if (lane == 0) red[w] = s;
    __syncthreads();
    s = red[0] + red[1] + red[2] + red[3];
    const float mu = s * (1.f / 512.f);
    const float d0 = v0 - mu, d1 = v1 - mu;
    __syncthreads();
    float vs = waveSum(d0 * d0 + d1 * d1);
    if (lane == 0) red[w] = vs;
    __syncthreads();
    vs = red[0] + red[1] + red[2] + red[3];
    const float rs = rsqrtf(vs * (1.f / 512.f) + 1e-5f);
    const float o0 = g[2 * t]     * d0 * rs + be[2 * t];
    const float o1 = g[2 * t + 1] * d1 * rs + be[2 * t + 1];
    xr[2 * t] = o0; xr[2 * t + 1] = o1;
    x16[(long)r * 512 + 2 * t]     = f2b(o0);
    x16[(long)r * 512 + 2 * t + 1] = f2b(o1);
    if constexpr (WRITE_OUT) {
        outp[(long)r * 512 + 2 * t]     = o0;
        outp[(long)r * 512 + 2 * t + 1] = o1;
    }
}

// x = copy(queries) fp32 + bf16
__global__ __launch_bounds__(256) void initx_k(
    const float* __restrict__ src, float* __restrict__ x, u16* __restrict__ x16)
{
    const long i = ((long)blockIdx.x * 256 + threadIdx.x) * 8;
    const float4 a = *(const float4*)(src + i);
    const float4 b = *(const float4*)(src + i + 4);
    *(float4*)(x + i) = a;
    *(float4*)(x + i + 4) = b;
    short8 r;
    r[0] = (short)f2b(a.x); r[1] = (short)f2b(a.y); r[2] = (short)f2b(a.z); r[3] = (short)f2b(a.w);
    r[4] = (short)f2b(b.x); r[5] = (short)f2b(b.y); r[6] = (short)f2b(b.z); r[7] = (short)f2b(b.w);
    *(short8*)(x16 + i) = r;
}

// W (K,N) fp32 -> WT (N,K) bf16, batched over blockIdx.z
__global__ __launch_bounds__(256) void transpose_w_k(
    const float* __restrict__ W, u16* __restrict__ WT, int K, int N)
{
    __shared__ float tile[32][33];
    const int z = blockIdx.z;
    W  += (size_t)z * K * N;
    WT += (size_t)z * K * N;
    const int n0 = blockIdx.x * 32, k0 = blockIdx.y * 32;
    const int tx = threadIdx.x & 31, ty = threadIdx.x >> 5;
#pragma unroll
    for (int j = 0; j < 32; j += 8)
        tile[ty + j][tx] = W[(size_t)(k0 + ty + j) * N + n0 + tx];
    __syncthreads();
#pragma unroll
    for (int j = 0; j < 32; j += 8)
        WT[(size_t)(n0 + ty + j) * K + k0 + tx] = f2b(tile[tx][ty + j]);
}

// ---------------------------------------------------------------------------
extern "C" void kernel_launch(void* const* d_in, const int* in_sizes, int n_in,
                              void* d_out, int out_size, void* d_ws, size_t ws_size,
                              hipStream_t stream)
{
    (void)in_sizes; (void)n_in; (void)out_size; (void)ws_size;
    const float* queries = (const float*)d_in[0];
    const float* feat    = (const float*)d_in[1];
    const float* extra   = (const float*)d_in[2];
    const float* Wq = (const float*)d_in[3];  const float* bq = (const float*)d_in[4];
    const float* Wk = (const float*)d_in[5];  const float* bk = (const float*)d_in[6];
    const float* Wv = (const float*)d_in[7];  const float* bv = (const float*)d_in[8];
    const float* Wo = (const float*)d_in[9];  const float* bo = (const float*)d_in[10];
    const float* W1 = (const float*)d_in[11]; const float* b1 = (const float*)d_in[12];
    const float* W2 = (const float*)d_in[13]; const float* b2 = (const float*)d_in[14];
    const float* g2 = (const float*)d_in[15]; const float* be2 = (const float*)d_in[16];
    const float* g3 = (const float*)d_in[17]; const float* be3 = (const float*)d_in[18];

    char* wsb = (char*)d_ws;
    size_t off = 0;
    auto alloc = [&](size_t bytes) -> char* {
        char* p = wsb + off; off += (bytes + 255) & ~(size_t)255; return p;
    };
    u16*  feat16 = (u16*)alloc(33554432ull * 2);   // (B*Nk, C) bf16
    u16*  WqT = (u16*)alloc(786432ull * 2);
    u16*  WkT = (u16*)alloc(786432ull * 2);
    u16*  WvT = (u16*)alloc(786432ull * 2);
    u16*  WoT = (u16*)alloc(786432ull * 2);
    u16*  W1T = (u16*)alloc(3145728ull * 2);
    u16*  W2T = (u16*)alloc(3145728ull * 2);
    u16*  K16 = (u16*)alloc(33554432ull * 2);      // (B,Nk,C)
    u16*  VT16 = (u16*)alloc(33554432ull * 2);     // (B,C,Nk); later FF2 partials
    u16*  q16 = (u16*)alloc(524288ull * 2);        // (B*Nq, C)
    float* Op  = (float*)alloc(4194304ull * 4);    // flash partials (4,128,64,64)
    float2* ml = (float2*)alloc(32768ull * 8);     // (4,128,64)
    float* affb  = (float*)alloc(196608ull * 4);
    u16*  o16 = (u16*)alloc(524288ull * 2);
    float* oproj = (float*)alloc(524288ull * 4);
    float* xb    = (float*)alloc(524288ull * 4);
    u16*  x16 = (u16*)alloc(524288ull * 2);
    u16*  h116 = (u16*)alloc(2097152ull * 2);
    float* ffb   = (float*)alloc(524288ull * 4);
    float* uvec  = (float*)alloc(24576ull * 4);
    float* cb    = (float*)alloc(48ull * 4);
    float* part2 = (float*)VT16;                   // alias: VT dead after flash

    float* out_f = (float*)d_out;
    float* outs_base  = out_f;                     // (3,16,64,512)
    float* attns_base = out_f + 1572864;           // (3,16,64,4096)
    float* affs_base  = out_f + 14155776;          // (3,16,1,1,4096)

    // prep (layer-independent)
    umat_k<<<dim3(3, 128), 256, 0, stream>>>(Wk, extra, uvec);
    cbk_k<<<12, 256, 0, stream>>>(bk, extra, cb);
    cvt16_aff_k<<<16384, 256, 0, stream>>>(feat, feat16, uvec, cb, affb, affs_base);
    initx_k<<<256, 256, 0, stream>>>(queries, xb, x16);
    transpose_w_k<<<dim3(16, 16, 3), 256, 0, stream>>>(Wq, WqT, 512, 512);
    transpose_w_k<<<dim3(16, 16, 3), 256, 0, stream>>>(Wk, WkT, 512, 512);
    transpose_w_k<<<dim3(16, 16, 3), 256, 0, stream>>>(Wv, WvT, 512, 512);
    transpose_w_k<<<dim3(16, 16, 3), 256, 0, stream>>>(Wo, WoT, 512, 512);
    transpose_w_k<<<dim3(64, 16, 3), 256, 0, stream>>>(W1, W1T, 512, 2048);
    transpose_w_k<<<dim3(16, 64, 3), 256, 0, stream>>>(W2, W2T, 2048, 512);

    for (int i = 0; i < 3; ++i) {
        // K = feat @ Wk + bk -> bf16 (B,Nk,C)
        gemm256x256_k<false, true, false><<<dim3(2, 256, 1), 512, 0, stream>>>(
            feat16, WkT + i * 262144, bk + i * 512, K16,
            512, 512, 512, 0, 0, 0, nullptr);
        // VT' = aff ⊙ ((feat @ Wv)^T + bv) -> (B,C,Nk)
        gemm256x256_k<true, true, true><<<dim3(16, 2, 16), 512, 0, stream>>>(
            WvT + i * 262144, feat16, bv + i * 512, VT16,
            512, 512, 4096, 0, 2097152, 2097152, affb + i * 65536);
        // q = x @ Wq + bq (raw)
        gemm_bt_k<64, 64, true, false, false, true>
            <<<dim3(8, 16, 1), 256, 0, stream>>>(
            x16, WqT + i * 262144, bq + i * 512, q16,
            512, 512, 512, 512, 0, 0, 0, 1.f);
        // attns[b] = (SCALE/8) q[b] @ K[b]^T -> fp32 (16,64,4096)
        gemm_bt_k<64, 128, false, false, false, false>
            <<<dim3(32, 1, 16), 256, 0, stream>>>(
            q16, K16, nullptr, attns_base + (size_t)i * 4194304,
            512, 512, 512, 4096, 32768, 2097152, 262144, 0.015625f);
        // flash attention (4 kv-splits) + merge -> o16
        fattn_k<<<dim3(4, 128), 256, 0, stream>>>(q16, K16, VT16, Op, ml);
        fmerge_k<<<512, 256, 0, stream>>>(Op, ml, o16);
        // o @ Wo + bo -> fp32
        gemm_bt_k<64, 64, false, false, false, true>
            <<<dim3(8, 16, 1), 256, 0, stream>>>(
            o16, WoT + i * 262144, bo + i * 512, oproj,
            512, 512, 512, 512, 0, 0, 0, 1.f);
        // x = LN(x + oproj; g2, beta2)
        ln_k<false><<<1024, 256, 0, stream>>>(xb, oproj, g2 + i * 512, be2 + i * 512, x16, nullptr);
        // h1 = relu(x @ W1 + b1) -> bf16
        gemm_bt_k<64, 128, true, true, false, true>
            <<<dim3(16, 16, 1), 256, 0, stream>>>(
            x16, W1T + (size_t)i * 1048576, b1 + i * 2048, h116,
            512, 512, 512, 2048, 0, 0, 0, 1.f);
        // ff partials = h1 @ W2 (split-K 4)
        gemm_bt_k<64, 64, false, false, false, false>
            <<<dim3(8, 16, 4), 256, 0, stream>>>(
            h116, W2T + (size_t)i * 1048576, nullptr, part2,
            512, 2048, 2048, 512, 512, 512, 524288, 1.f);
        ffred_k<<<512, 256, 0, stream>>>(part2, b2 + i * 512, ffb);
        // x = LN(x + ff; g3, beta3), write outs[i]
        ln_k<true><<<1024, 256, 0, stream>>>(xb, ffb, g3 + i * 512, be3 + i * 512, x16,
                                             outs_base + (size_t)i * 524288);
    }
}